// Round 11
// baseline (1235.232 us; speedup 1.0000x reference)
//
#include <hip/hip_runtime.h>
#include <hip/hip_bf16.h>

// Decoder (LSTM + attention captioner), MI355X. Round 23:
//  - r22 post-mortem: 1284.3 -> 1142.7 (-142, predicted -30..50). Overshoot
//    => per-dispatch cost ~10-15us (graph replay + drain). Dispatch count is
//    the dominant tunable outside the loop.
//  - r23: (1) pre-pass 11 -> 3 dispatches: k_pre1 (zero|ln|mean|cvt|wg|prep
//    segmented, 512thr), k_pre2 (KF|init|EU; KF keeps bids 0..143 for XCD
//    map), k_pre3 (QG2|sc12). (2) post 3 -> 2: k_G1 = full-K G1m (36 kt, 30
//    blocks) + fused bias/emb epilogue -> outo bf16; kills k_G1red + g1p.
//    Loop unchanged (2/step is the dependency minimum).

#define NB 64
#define NP 144
#define DE 1792
#define DD 512
#define DA 512
#define EM 300
#define NV 32000
#define NTT 30
#define NS 29
#define G4 2048
#define KP 320
#define KG1 2304
#define LN_EPS 1e-5f
#define RSCALE 0.044194173824159216f   // 1/sqrt(512)
#define KSPL 12       // K splits in k_B (2304 = 12 x 192)

typedef __attribute__((ext_vector_type(8))) short short8;
typedef __attribute__((ext_vector_type(4))) float f32x4;
typedef __attribute__((ext_vector_type(8))) unsigned short ushort8v;

__device__ __forceinline__ float bf2f(unsigned short u){
  union { unsigned int i; float f; } w; w.i = ((unsigned int)u) << 16; return w.f;
}
__device__ __forceinline__ unsigned short f2bf(float f){
  union { float f; unsigned int i; } u; u.f = f;
  unsigned int r = u.i + 0x7FFFu + ((u.i >> 16) & 1u);
  return (unsigned short)(r >> 16);
}
__device__ __forceinline__ float sigm(float x){ return 1.f/(1.f + __expf(-x)); }

__device__ __forceinline__ float wave_reduce_sum(float v){
  #pragma unroll
  for (int o = 32; o >= 1; o >>= 1) v += __shfl_xor(v, o);
  return v;
}
__device__ __forceinline__ float wave_reduce_max(float v){
  #pragma unroll
  for (int o = 32; o >= 1; o >>= 1) v = fmaxf(v, __shfl_xor(v, o));
  return v;
}
__device__ __forceinline__ float block_sum512(float v, float* sbuf8){
  v = wave_reduce_sum(v);
  const int lane = threadIdx.x & 63, wid = threadIdx.x >> 6;
  if (lane == 0) sbuf8[wid] = v;
  __syncthreads();
  float r = 0.f;
  #pragma unroll
  for (int i = 0; i < 8; ++i) r += sbuf8[i];
  __syncthreads();
  return r;
}

// ---- shared MFMA 64x64-tile helpers (validated r4..r10) ----
__device__ __forceinline__ void stage_tile(const unsigned short* __restrict__ src,
    int row_stride, int k0, char* lds){
  const int tid = threadIdx.x;
  #pragma unroll
  for (int c = 0; c < 2; ++c){
    const int o = tid + c*256;
    const int m = o >> 3, ks8 = o & 7;
    const ushort8v v = *(const ushort8v*)&src[(size_t)m*row_stride + k0 + ks8*8];
    *(ushort8v*)&lds[m*128 + ((ks8 ^ (m&7))<<4)] = v;
  }
}
__device__ __forceinline__ void mma64(const char* Alds, const char* Blds,
    int w, int lane, f32x4 acc[4]){
  #pragma unroll
  for (int ks = 0; ks < 2; ++ks){
    const int slot = ks*4 + (lane>>4);
    const int n = w*16 + (lane&15);
    const short8 bfv = *(const short8*)&Blds[n*128 + ((slot ^ (n&7))<<4)];
    #pragma unroll
    for (int fm = 0; fm < 4; ++fm){
      const int m = fm*16 + (lane&15);
      const short8 afv = *(const short8*)&Alds[m*128 + ((slot ^ (m&7))<<4)];
      acc[fm] = __builtin_amdgcn_mfma_f32_16x16x32_bf16(afv, bfv, acc[fm], 0, 0, 0);
    }
  }
}

// ---- big-tile GEMM body (k_G2-validated): 128M x 256N tile.
template <int NKT>
__device__ __forceinline__ void gemm_big(const unsigned short* __restrict__ A,
    const unsigned short* __restrict__ B, int sa, int sb,
    char* Alds, char* Blds, int mt, int nt, f32x4 acc[8][4]){
  const int tid = threadIdx.x, w = tid>>6, lane = tid&63;
  for (int kt = 0; kt < NKT; ++kt){
    const int k0 = kt*64;
    __syncthreads();
    #pragma unroll
    for (int c2 = 0; c2 < 4; ++c2){
      const int o16 = tid + c2*256;
      const int m = o16>>3, ks8 = o16&7;
      const ushort8v v = *(const ushort8v*)&A[(size_t)(mt*128+m)*sa + k0 + ks8*8];
      *(ushort8v*)&Alds[m*128 + ((ks8 ^ (m&7))<<4)] = v;
    }
    #pragma unroll
    for (int c2 = 0; c2 < 8; ++c2){
      const int o16 = tid + c2*256;
      const int n = o16>>3, ks8 = o16&7;
      const ushort8v v = *(const ushort8v*)&B[(size_t)(nt*256+n)*sb + k0 + ks8*8];
      *(ushort8v*)&Blds[n*128 + ((ks8 ^ (n&7))<<4)] = v;
    }
    __syncthreads();
    #pragma unroll
    for (int ks = 0; ks < 2; ++ks){
      const int slot = ks*4 + (lane>>4);
      short8 af[8];
      #pragma unroll
      for (int fm = 0; fm < 8; ++fm){
        const int m = fm*16 + (lane&15);
        af[fm] = *(const short8*)&Alds[m*128 + ((slot ^ (m&7))<<4)];
      }
      #pragma unroll
      for (int fn = 0; fn < 4; ++fn){
        const int n = w*64 + fn*16 + (lane&15);
        const short8 bfv = *(const short8*)&Blds[n*128 + ((slot ^ (n&7))<<4)];
        #pragma unroll
        for (int fm = 0; fm < 8; ++fm)
          acc[fm][fn] = __builtin_amdgcn_mfma_f32_16x16x32_bf16(af[fm], bfv, acc[fm][fn], 0, 0, 0);
      }
    }
  }
}

// ======== PRE stage 1: zero | ln_feats | mean | cvt_all | wg | prep.
// 512 threads. blocks: zero[0,4000) ln[4000,13216) mean[13216,13440)
// cvt[13440,17656) wg[17656,18168) prep[18168,18169).
__global__ __launch_bounds__(512) void k_pre1(
    const float* __restrict__ feats, const float* __restrict__ ln_kv_g,
    const float* __restrict__ ln_kv_b,
    const float* __restrict__ W_Lo, const float* __restrict__ Wh,
    const float* __restrict__ Wu,  const float* __restrict__ Wa,
    const float* __restrict__ Wk,  const float* __restrict__ W_Lh,
    const float* __restrict__ W_Lz,
    const float* __restrict__ Wq, const float* __restrict__ bk,
    const float* __restrict__ g,  const float* __restrict__ bln,
    const float* __restrict__ bq, const float* __restrict__ Wbeta,
    const float* __restrict__ bbeta,
    float* __restrict__ pred, float* __restrict__ alph,
    unsigned short* __restrict__ feats_bf, float* __restrict__ mean_a,
    unsigned short* __restrict__ wlo_t, unsigned short* __restrict__ whT,
    unsigned short* __restrict__ wut,   unsigned short* __restrict__ wat,
    unsigned short* __restrict__ WkT,   unsigned short* __restrict__ WLt,
    unsigned short* __restrict__ Wg, float* __restrict__ vq,
    float* __restrict__ u_, float* __restrict__ voff,
    float* __restrict__ gw, float* __restrict__ cscal){
  __shared__ float t[64][65];
  __shared__ float sbuf8[8];
  const int tid = threadIdx.x;
  int lb = blockIdx.x;
  if (lb < 4000){                       // ---- zero outputs
    const int idx = lb*512 + tid;
    { const int b = idx / NV, v = idx - b*NV;
      pred[(size_t)b*NTT*NV + v] = 0.f; }
    if (idx < NB*NP){
      const int b = idx / NP, p = idx - b*NP;
      alph[(size_t)b*NTT*NP + p] = 0.f; }
    return;
  }
  lb -= 4000;
  if (lb < 9216){                       // ---- LayerNorm(features) -> bf16
    const float* x = feats + (size_t)lb * DE;
    float v[4]; float s = 0.f;
    #pragma unroll
    for (int i = 0; i < 4; ++i){
      const int idx = i*512 + tid;
      v[i] = (idx < DE) ? x[idx] : 0.f;
      s += v[i];
    }
    const float mean = block_sum512(s, sbuf8) * (1.f/DE);
    float q = 0.f;
    #pragma unroll
    for (int i = 0; i < 4; ++i){
      const int idx = i*512 + tid;
      if (idx < DE){ const float d = v[i] - mean; q += d*d; }
    }
    const float var = block_sum512(q, sbuf8) * (1.f/DE);
    const float rinv = rsqrtf(var + LN_EPS);
    #pragma unroll
    for (int i = 0; i < 4; ++i){
      const int idx = i*512 + tid;
      if (idx < DE)
        feats_bf[(size_t)lb*DE + idx] = f2bf((v[i]-mean)*rinv*ln_kv_g[idx] + ln_kv_b[idx]);
    }
    return;
  }
  lb -= 9216;
  if (lb < 224){                        // ---- mean over patches
    const int idx = lb*512 + tid;
    const int b = idx / DE, d = idx - b*DE;
    const float* p = feats + (size_t)b*NP*DE + d;
    float s = 0.f;
    for (int pp = 0; pp < NP; ++pp) s += p[(size_t)pp*DE];
    mean_a[idx] = s * (1.f/NP);
    return;
  }
  lb -= 224;
  if (lb < 4216){                       // ---- all weight transposes
    if (lb >= 4036){
      int l2 = lb - 4036;
      const int e0 = (l2 % 5)*64, k0 = (l2 / 5)*64;
      for (int i = tid; i < 4096; i += 512){
        const int k = i>>6, e2 = i&63;
        const int kg = k0 + k, e = e0 + e2;
        float v = 0.f;
        if (e < EM) v = (kg < DD) ? W_Lh[(size_t)kg*EM + e] : W_Lz[(size_t)(kg-DD)*EM + e];
        t[k][e2] = v;
      }
      __syncthreads();
      for (int i = tid; i < 4096; i += 512){
        const int e2 = i>>6, k = i&63;
        WLt[(size_t)(e0+e2)*KG1 + k0+k] = f2bf(t[k][e2]);
      }
      return;
    }
    const float* src; unsigned short* dst; int K, N, KPad, nx;
    if      (lb < 2500){             src=W_Lo; dst=wlo_t; K=EM; N=NV; KPad=KP; nx=500; }
    else if (lb < 2756){ lb -= 2500; src=Wh;   dst=whT;   K=DD; N=G4; KPad=DD; nx=32; }
    else if (lb < 2916){ lb -= 2756; src=Wu;   dst=wut;   K=EM; N=G4; KPad=KP; nx=32; }
    else if (lb < 3812){ lb -= 2916; src=Wa;   dst=wat;   K=DE; N=G4; KPad=DE; nx=32; }
    else               { lb -= 3812; src=Wk;   dst=WkT;   K=DE; N=DD; KPad=DE; nx=8;  }
    const int n0 = (lb % nx)*64, k0 = (lb / nx)*64;
    for (int i = tid; i < 4096; i += 512){
      const int k = i>>6, n = i&63;
      t[k][n] = (k0 + k < K) ? src[(size_t)(k0+k)*N + n0+n] : 0.f;
    }
    __syncthreads();
    for (int i = tid; i < 4096; i += 512){
      const int n = i>>6, k = i&63;
      dst[(size_t)(n0+n)*KPad + k0+k] = f2bf(t[k][n]);
    }
    return;
  }
  lb -= 4216;
  if (lb < 512){                        // ---- Wg = diag(g) * Wq
    const int idx = lb*512 + tid;
    const int k = idx >> 9;
    Wg[idx] = f2bf(g[k]*Wq[idx]);
    return;
  }
  // ---- prep: vq + u/voff/gw/cscal (1 block)
  {
    const int a = tid;
    {
      const float* row = Wq + (size_t)a*DA;
      float acc = 0.f;
      for (int j = 0; j < DA; ++j) acc = fmaf(row[j], bk[j], acc);
      vq[a] = acc;
    }
    float uu = 0.f, vv = 0.f;
    for (int k = 0; k < DD; ++k){
      const float wv = Wq[(size_t)k*DA + a];
      uu = fmaf(g[k],   wv, uu);
      vv = fmaf(bln[k], wv, vv);
    }
    const float vo = vv + bq[a];
    u_[a]   = uu;
    voff[a] = vo;
    gw[a]   = g[a]*Wbeta[a];
    const float c1 = block_sum512(g[a]*Wbeta[a], sbuf8);
    const float c2 = block_sum512(bln[a]*Wbeta[a], sbuf8);
    const float c3 = block_sum512(uu*bk[a], sbuf8);
    const float c4 = block_sum512(vo*bk[a], sbuf8);
    if (a == 0){ cscal[0]=c1; cscal[1]=c2+bbeta[0]; cscal[2]=c3; cscal[3]=c4; }
  }
}

// ======== PRE stage 2: KF | init_g | EU.  256 threads.
// blocks: KF[0,144) (keeps bid%8 XCD map), init[144,160), EU[160,1088).
__global__ __launch_bounds__(256) void k_pre2(
    const unsigned short* __restrict__ fb, const unsigned short* __restrict__ WkT,
    const float* __restrict__ mean_a,
    const float* __restrict__ W_ih, const float* __restrict__ b_ih,
    const float* __restrict__ W_ic, const float* __restrict__ b_ic,
    const float* __restrict__ emb_table, const int* __restrict__ captions,
    const unsigned short* __restrict__ wut,
    unsigned short* __restrict__ KF, float* __restrict__ hbuf,
    unsigned short* __restrict__ hstbf, float* __restrict__ cb0,
    float* __restrict__ eu){
  __shared__ alignas(16) char smem[49152];
  const int tid = threadIdx.x, w = tid>>6, lane = tid&63;
  int lb = blockIdx.x;
  if (lb < 144){                        // ---- KF big-tile
    char* Alds = smem; char* Blds = smem + 16384;
    const int wgid = (lb & 7)*18 + (lb >> 3);
    const int nt = wgid & 1, mt = wgid >> 1;
    f32x4 acc[8][4];
    #pragma unroll
    for (int i = 0; i < 8; ++i)
      #pragma unroll
      for (int j = 0; j < 4; ++j) acc[i][j] = (f32x4)(0.f);
    gemm_big<28>(fb, WkT, DE, DE, Alds, Blds, mt, nt, acc);
    const int ncol0 = nt*256 + w*64 + (lane&15);
    #pragma unroll
    for (int fm = 0; fm < 8; ++fm)
      #pragma unroll
      for (int r = 0; r < 4; ++r){
        const int row = mt*128 + fm*16 + (lane>>4)*4 + r;
        #pragma unroll
        for (int fn = 0; fn < 4; ++fn)
          KF[(size_t)row*DD + ncol0 + fn*16] = f2bf(acc[fm][fn][r]);
      }
    return;
  }
  lb -= 144;
  if (lb < 16){                         // ---- h0/c0 GEMM
    float* la = (float*)smem;                 // 64*68 floats
    float* lw = (float*)smem + 64*68;
    const int which = lb >> 3;
    const float* W    = which ? W_ic : W_ih;
    const float* bias = which ? b_ic : b_ih;
    float* out = which ? cb0 : hbuf;
    unsigned short* outbf = which ? nullptr : hstbf;
    const int j0 = (lb & 7)*64;
    const int tr = tid&15, tn = tid>>4;
    float acc[16] = {0.f};
    for (int a0 = 0; a0 < DE; a0 += 64){
      __syncthreads();
      for (int i = tid; i < 4096; i += 256){
        const int b = i>>6, k = i&63;
        la[k*68 + b] = mean_a[(size_t)b*DE + a0+k];
      }
      for (int i = tid; i < 4096; i += 256){
        const int k = i>>6, j = i&63;
        lw[k*68 + j] = W[(size_t)(a0+k)*DD + j0+j];
      }
      __syncthreads();
      for (int k = 0; k < 64; ++k){
        float av[4], bv[4];
        #pragma unroll
        for (int ii = 0; ii < 4; ++ii) av[ii] = la[k*68 + tr*4+ii];
        #pragma unroll
        for (int jj = 0; jj < 4; ++jj) bv[jj] = lw[k*68 + tn*4+jj];
        #pragma unroll
        for (int ii = 0; ii < 4; ++ii)
          #pragma unroll
          for (int jj = 0; jj < 4; ++jj)
            acc[ii*4+jj] = fmaf(av[ii], bv[jj], acc[ii*4+jj]);
      }
    }
    #pragma unroll
    for (int ii = 0; ii < 4; ++ii)
      #pragma unroll
      for (int jj = 0; jj < 4; ++jj){
        const size_t idx = (size_t)(tr*4+ii)*DD + j0 + tn*4+jj;
        const float val = acc[ii*4+jj] + bias[j0 + tn*4+jj];
        out[idx] = val;
        if (outbf) outbf[idx] = f2bf(val);
      }
    return;
  }
  lb -= 16;
  {                                     // ---- EU: emb(s)@Wu
    char* Alds = smem; char* Blds = smem + 8192;
    int* capL = (int*)(smem + 16384);
    const int jt = lb & 31, s = lb >> 5;
    if (tid < 64) capL[tid] = captions[tid*NTT + s];
    f32x4 acc[4];
    #pragma unroll
    for (int i = 0; i < 4; ++i) acc[i] = (f32x4)(0.f);
    for (int kt = 0; kt < 5; ++kt){
      __syncthreads();
      #pragma unroll
      for (int c = 0; c < 2; ++c){
        const int o = tid + c*256;
        const int m = o>>3, ks8 = o&7;
        const int e0 = kt*64 + ks8*8;
        const float* er = emb_table + (size_t)capL[m]*EM;
        ushort8v v;
        #pragma unroll
        for (int jj = 0; jj < 8; ++jj)
          v[jj] = (e0 + jj < EM) ? f2bf(er[e0 + jj]) : (unsigned short)0;
        *(ushort8v*)&Alds[m*128 + ((ks8 ^ (m&7))<<4)] = v;
      }
      stage_tile(wut + (size_t)jt*64*KP, KP, kt*64, Blds);
      __syncthreads();
      mma64(Alds, Blds, w, lane, acc);
    }
    const int j = jt*64 + w*16 + (lane&15);
    #pragma unroll
    for (int fm = 0; fm < 4; ++fm)
      #pragma unroll
      for (int r = 0; r < 4; ++r){
        const int b = fm*16 + (lane>>4)*4 + r;
        eu[((size_t)s*NB + b)*G4 + j] = acc[fm][r];
      }
  }
}

// ======== PRE stage 3: QG2 | sc12.  256 threads.
// blocks: QG2[0,144), sc12[144,2448) (4 rows/block, wave-level).
__global__ __launch_bounds__(256) void k_pre3(
    const unsigned short* __restrict__ KF, const unsigned short* __restrict__ Wg,
    const float* __restrict__ g_, const float* __restrict__ vq,
    const float* __restrict__ u_, const float* __restrict__ voff,
    const float* __restrict__ cscal,
    unsigned short* __restrict__ G2, float2* __restrict__ sc12){
  __shared__ alignas(16) char smem[49152];
  const int tid = threadIdx.x, w = tid>>6, lane = tid&63;
  int lb = blockIdx.x;
  if (lb < 144){                        // ---- G2 big-tile
    char* Alds = smem; char* Blds = smem + 16384;
    const int wgid = (lb & 7)*18 + (lb >> 3);
    const int nt = wgid & 1, mt = wgid >> 1;
    f32x4 acc[8][4];
    #pragma unroll
    for (int i = 0; i < 8; ++i)
      #pragma unroll
      for (int j = 0; j < 4; ++j) acc[i][j] = (f32x4)(0.f);
    gemm_big<8>(KF, Wg, DD, DD, Alds, Blds, mt, nt, acc);
    const int ncol0 = nt*256 + w*64 + (lane&15);
    float addv[4];
    #pragma unroll
    for (int fn = 0; fn < 4; ++fn){
      const int q = ncol0 + fn*16;
      addv[fn] = g_[q]*vq[q];
    }
    #pragma unroll
    for (int fm = 0; fm < 8; ++fm)
      #pragma unroll
      for (int r = 0; r < 4; ++r){
        const int row = mt*128 + fm*16 + (lane>>4)*4 + r;
        #pragma unroll
        for (int fn = 0; fn < 4; ++fn)
          G2[(size_t)row*DD + ncol0 + fn*16] = f2bf(acc[fm][fn][r] + addv[fn]);
      }
    return;
  }
  lb -= 144;
  {                                     // ---- sc12, 4 rows/block
    const int row = lb*4 + w;
    const unsigned short* kf = KF + (size_t)row*DD + lane*8;
    float s1 = 0.f, s2 = 0.f;
    #pragma unroll
    for (int j = 0; j < 8; ++j){
      const float kv = bf2f(kf[j]);
      s1 = fmaf(u_[lane*8 + j],   kv, s1);
      s2 = fmaf(voff[lane*8 + j], kv, s2);
    }
    s1 = wave_reduce_sum(s1);
    s2 = wave_reduce_sum(s2);
    if (lane == 0){
      float2 o; o.x = s1 + cscal[2]; o.y = s2 + cscal[3];
      sc12[row] = o;
    }
  }
}

// ======== per-step kernel A (r21 structure; gp bf16)
__global__ __launch_bounds__(512) void k_A(
    const unsigned short* __restrict__ gp, const float* __restrict__ eu,
    const float* __restrict__ b_gates, const float* __restrict__ cin,
    float* __restrict__ cout, unsigned short* __restrict__ hst,
    const unsigned short* __restrict__ G2, const float2* __restrict__ sc12,
    const unsigned short* __restrict__ fb, const float* __restrict__ gw,
    const float* __restrict__ cscal, const int s, const int do_att,
    float* __restrict__ alph, unsigned short* __restrict__ zbf){
  __shared__ alignas(16) unsigned short hL[DD];
  __shared__ float sc[NP];
  __shared__ float al[NP];
  __shared__ float sredA[8*4];
  __shared__ float sbufM[8];
  __shared__ float sbufS[8];
  int sl, b;
  if (gridDim.x == 1){ sl = 0; b = blockIdx.y; }
  else {
    const int lin = blockIdx.x + 2*blockIdx.y;
    const int xcd = lin & 7, i = lin >> 3;
    b = xcd*8 + (i & 7);
    sl = i >> 3;
  }
  const int tid = threadIdx.x;
  const int w = tid>>6, lane = tid&63;
  float hn;
  if (s == 0){
    const unsigned short hb = hst[(size_t)b*DD + tid];
    hn = bf2f(hb);
    hL[tid] = hb;
  } else {
    const int m = s - 1;
    unsigned short gv[4*KSPL];
    #pragma unroll
    for (int ks = 0; ks < KSPL; ++ks){
      const unsigned short* gr = gp + ((size_t)ks*NB + b)*G4 + tid;
      gv[ks*4+0] = gr[0];
      gv[ks*4+1] = gr[DD];
      gv[ks*4+2] = gr[2*DD];
      gv[ks*4+3] = gr[3*DD];
    }
    const float* eur = eu + ((size_t)m*NB + b)*G4 + tid;
    float gs0 = b_gates[tid]        + eur[0];
    float gs1 = b_gates[DD + tid]   + eur[DD];
    float gs2 = b_gates[2*DD + tid] + eur[2*DD];
    float gs3 = b_gates[3*DD + tid] + eur[3*DD];
    #pragma unroll
    for (int ks = 0; ks < KSPL; ++ks){
      gs0 += bf2f(gv[ks*4+0]); gs1 += bf2f(gv[ks*4+1]);
      gs2 += bf2f(gv[ks*4+2]); gs3 += bf2f(gv[ks*4+3]);
    }
    const size_t idx = (size_t)b*DD + tid;
    const float cn = sigm(gs1)*cin[idx] + sigm(gs0)*tanhf(gs3);
    hn = sigm(gs2)*tanhf(cn);
    cout[idx] = cn;
    const unsigned short hb = f2bf(hn);
    hst[(size_t)s*NB*DD + idx] = hb;
    hL[tid] = hb;
  }
  if (!do_att) return;
  float p1 = hn, p2 = hn*hn, p3 = hn*gw[tid];
  #pragma unroll
  for (int o = 32; o >= 1; o >>= 1){
    p1 += __shfl_xor(p1, o);
    p2 += __shfl_xor(p2, o);
    p3 += __shfl_xor(p3, o);
  }
  if (lane == 0){ sredA[w*4] = p1; sredA[w*4+1] = p2; sredA[w*4+2] = p3; }
  __syncthreads();
  float S1 = 0.f, S2 = 0.f, S3 = 0.f;
  #pragma unroll
  for (int i = 0; i < 8; ++i){
    S1 += sredA[i*4]; S2 += sredA[i*4+1]; S3 += sredA[i*4+2];
  }
  const float mean = S1*(1.f/512.f);
  const float var  = S2*(1.f/512.f) - mean*mean;
  const float rinv = rsqrtf(var + LN_EPS);
  const float beta = sigm(rinv*(S3 - mean*cscal[0]) + cscal[1]);
  const short8 hv = *(const short8*)&hL[lane*8];
  #pragma unroll 1
  for (int i0 = 0; i0 < 18; i0 += 9){
    short8 U[9];
    float2 SV[9];
    #pragma unroll
    for (int j = 0; j < 9; ++j){
      const int p = w + 8*(i0+j);
      U[j] = *(const short8*)&G2[(size_t)(b*NP + p)*DD + lane*8];
      if (lane == 0) SV[j] = sc12[b*NP + p];
    }
    #pragma unroll
    for (int j = 0; j < 9; ++j){
      float a2 = 0.f;
      #pragma unroll
      for (int q = 0; q < 8; ++q)
        a2 = fmaf(bf2f((unsigned short)U[j][q]), bf2f((unsigned short)hv[q]), a2);
      a2 = wave_reduce_sum(a2);
      if (lane == 0)
        sc[w + 8*(i0+j)] = RSCALE*(rinv*a2 - rinv*mean*SV[j].x + SV[j].y);
    }
  }
  __syncthreads();
  const float v = (tid < NP) ? sc[tid] : -1e30f;
  const float mv = wave_reduce_max(v);
  if (lane == 0) sbufM[w] = mv;
  __syncthreads();
  float mm = sbufM[0];
  #pragma unroll
  for (int i = 1; i < 8; ++i) mm = fmaxf(mm, sbufM[i]);
  const float e = (tid < NP) ? __expf(v - mm) : 0.f;
  const float sv = wave_reduce_sum(e);
  if (lane == 0) sbufS[w] = sv;
  __syncthreads();
  float ssum = 0.f;
  #pragma unroll
  for (int i = 0; i < 8; ++i) ssum += sbufS[i];
  if (tid < NP){
    const float a3 = e / ssum;
    al[tid] = a3;
    if (sl == 0) alph[((size_t)b*NTT + s + 1)*NP + tid] = a3;
  }
  __syncthreads();
  if (tid < 448){
    const int d0 = sl*896 + tid*2;
    const unsigned short* fB = fb + (size_t)b*NP*DE + d0;
    float a0 = 0.f, a1 = 0.f;
    #pragma unroll 1
    for (int p0 = 0; p0 < NP; p0 += 36){
      ushort2 fv[36];
      #pragma unroll
      for (int j = 0; j < 36; ++j) fv[j] = *(const ushort2*)&fB[(size_t)(p0+j)*DE];
      #pragma unroll
      for (int j = 0; j < 36; ++j){
        const float ap = al[p0+j];
        a0 = fmaf(ap, bf2f(fv[j].x), a0);
        a1 = fmaf(ap, bf2f(fv[j].y), a1);
      }
    }
    ushort2 zo;
    zo.x = f2bf(a0*beta);
    zo.y = f2bf(a1*beta);
    *(ushort2*)&zbf[((size_t)s*NB + b)*DE + d0] = zo;
  }
}

// ======== per-step kernel B (K-split 12, bf16 gp out).  grid (32, 12).
__global__ __launch_bounds__(256) void k_B(
    const unsigned short* __restrict__ hst, const unsigned short* __restrict__ zbf,
    const unsigned short* __restrict__ whT, const unsigned short* __restrict__ wat,
    const int s, unsigned short* __restrict__ gp){
  __shared__ char Alds[8192];
  __shared__ char Blds[8192];
  const int jt = blockIdx.x, ks = blockIdx.y;
  const int tid = threadIdx.x, w = tid>>6, lane = tid&63;
  const unsigned short* hrow = hst + (size_t)s*NB*DD;
  const unsigned short* zrow = zbf + (size_t)s*NB*DE;
  f32x4 acc[4];
  #pragma unroll
  for (int i = 0; i < 4; ++i) acc[i] = (f32x4)(0.f);
  for (int kt = 0; kt < 3; ++kt){
    const int k0 = ks*192 + kt*64;
    __syncthreads();
    if (k0 < DD) stage_tile(hrow, DD, k0, Alds);
    else         stage_tile(zrow, DE, k0 - DD, Alds);
    #pragma unroll
    for (int c2 = 0; c2 < 2; ++c2){
      const int o = tid + c2*256;
      const int m = o>>3, ks8 = o&7;
      const int col = (m>>4)*DD + jt*16 + (m&15);
      const unsigned short* src = (k0 < DD)
          ? whT + (size_t)col*DD + k0
          : wat + (size_t)col*DE + (k0 - DD);
      const ushort8v v = *(const ushort8v*)&src[ks8*8];
      *(ushort8v*)&Blds[m*128 + ((ks8 ^ (m&7))<<4)] = v;
    }
    __syncthreads();
    mma64(Alds, Blds, w, lane, acc);
  }
  const int jcol = jt*16 + (lane&15);
  unsigned short* gps = gp + (size_t)ks*NB*G4;
  #pragma unroll
  for (int fm = 0; fm < 4; ++fm)
    #pragma unroll
    for (int r = 0; r < 4; ++r){
      const int b = fm*16 + (lane>>4)*4 + r;
      gps[(size_t)b*G4 + w*DD + jcol] = f2bf(acc[fm][r]);
    }
}

// ---- post G1: out_o, full-K big-tile + fused bias/emb epilogue -> outo bf16.
// grid (15 mt, 2 nt).  M=1856 guard, N=320 guard (B-row clamp).
__global__ __launch_bounds__(256) void k_G1(const unsigned short* __restrict__ hstbf,
    const unsigned short* __restrict__ zbf, const unsigned short* __restrict__ WLt,
    const float* __restrict__ b_Lh, const float* __restrict__ b_Lz,
    const float* __restrict__ emb_table, const int* __restrict__ captions,
    unsigned short* __restrict__ outo){
  __shared__ char Alds[128*128];
  __shared__ char Blds[256*128];
  const int mt = blockIdx.x, nt = blockIdx.y;
  const int tid = threadIdx.x, w = tid>>6, lane = tid&63;
  f32x4 acc[8][4];
  #pragma unroll
  for (int i = 0; i < 8; ++i)
    #pragma unroll
    for (int j = 0; j < 4; ++j) acc[i][j] = (f32x4)(0.f);
  for (int kt = 0; kt < 36; ++kt){
    const int k0 = kt*64;                  // 64-aligned; never straddles DD
    __syncthreads();
    #pragma unroll
    for (int c2 = 0; c2 < 4; ++c2){
      const int o16 = tid + c2*256;
      const int m = o16>>3, ks8 = o16&7;
      const int r = mt*128 + m;
      ushort8v v;
      if (r < NS*NB){
        const int sS = r >> 6, bb = r & 63;
        const unsigned short* srcp = (k0 < DD)
            ? hstbf + ((size_t)(sS+1)*NB + bb)*DD + k0
            : zbf + ((size_t)sS*NB + bb)*DE + (k0 - DD);
        v = *(const ushort8v*)&srcp[ks8*8];
      } else {
        #pragma unroll
        for (int j = 0; j < 8; ++j) v[j] = 0;
      }
      *(ushort8v*)&Alds[m*128 + ((ks8 ^ (m&7))<<4)] = v;
    }
    #pragma unroll
    for (int c2 = 0; c2 < 8; ++c2){
      const int o16 = tid + c2*256;
      const int n = o16>>3, ks8 = o16&7;
      int nr = nt*256 + n;
      if (nr >= KP) nr = KP - 1;           // clamp (discarded by guard)
      const ushort8v v = *(const ushort8v*)&WLt[(size_t)nr*KG1 + k0 + ks8*8];
      *(ushort8v*)&Blds[n*128 + ((ks8 ^ (n&7))<<4)] = v;
    }
    __syncthreads();
    #pragma unroll
    for (int ks = 0; ks < 2; ++ks){
      const int slot = ks*4 + (lane>>4);
      short8 af[8];
      #pragma unroll
      for (int fm = 0; fm < 8; ++fm){
        const int m = fm*16 + (lane&15);
        af[fm] = *(const short8*)&Alds[m*128 + ((slot ^ (m&7))<<4)];
      }
      #pragma unroll
      for (int fn = 0; fn < 4; ++fn){
        const int n = w*64 + fn*16 + (lane&15);
        const short8 bfv = *(const short8*)&Blds[n*128 + ((slot ^ (n&7))<<4)];
        #pragma unroll
        for (int fm = 0; fm < 8; ++fm)
          acc[fm][fn] = __builtin_amdgcn_mfma_f32_16x16x32_bf16(af[fm], bfv, acc[fm][fn], 0, 0, 0);
      }
    }
  }
  const int ncol0 = nt*256 + w*64 + (lane&15);
  #pragma unroll
  for (int fm = 0; fm < 8; ++fm){
    #pragma unroll
    for (int r = 0; r < 4; ++r){
      const int row = mt*128 + fm*16 + (lane>>4)*4 + r;
      if (row < NS*NB){
        const int s = row >> 6, b = row & 63;
        const int cap = captions[b*NTT + s];
        #pragma unroll
        for (int fn = 0; fn < 4; ++fn){
          const int e = ncol0 + fn*16;
          if (e < KP){
            float v = 0.f;
            if (e < EM)
              v = acc[fm][fn][r] + b_Lh[e] + b_Lz[e] + emb_table[(size_t)cap*EM + e];
            outo[(size_t)row*KP + e] = f2bf(v);
          }
        }
      }
    }
  }
}

// ---- post G2: logits MFMA, M-tile 128.  1D grid 1875, bijective XCD
// swizzle (r18).  NONTEMPORAL stores.
__global__ __launch_bounds__(256) void k_G2(const unsigned short* __restrict__ Abf,
    const unsigned short* __restrict__ Bt, const float* __restrict__ b_Lo,
    float* __restrict__ pred){
  __shared__ char Alds[128*128];
  __shared__ char Blds[256*128];
  const int bid = blockIdx.x;
  const int xcd = bid & 7, idx8 = bid >> 3;
  const int wgid = (xcd < 3 ? xcd*235 : 705 + (xcd-3)*234) + idx8;
  const int nt = wgid / 15, mt = wgid - nt*15;
  const int tid = threadIdx.x, w = tid>>6, lane = tid&63;
  f32x4 acc[8][4];
  #pragma unroll
  for (int i = 0; i < 8; ++i)
    #pragma unroll
    for (int j = 0; j < 4; ++j)
      acc[i][j] = (f32x4)(0.f);
  gemm_big<5>(Abf, Bt, KP, KP, Alds, Blds, mt, nt, acc);
  const int ncol0 = nt*256 + w*64 + (lane&15);
  #pragma unroll
  for (int fm = 0; fm < 8; ++fm){
    #pragma unroll
    for (int r = 0; r < 4; ++r){
      const int row = mt*128 + fm*16 + (lane>>4)*4 + r;
      if (row < NS*NB){
        const int s = row >> 6, b = row & 63;
        float* prow = &pred[((size_t)b*NTT + s + 1)*NV + ncol0];
        #pragma unroll
        for (int fn = 0; fn < 4; ++fn)
          __builtin_nontemporal_store(acc[fm][fn][r] + b_Lo[ncol0 + fn*16],
                                      &prow[fn*16]);
      }
    }
  }
}

extern "C" void kernel_launch(void* const* d_in, const int* in_sizes, int n_in,
                              void* d_out, int out_size, void* d_ws, size_t ws_size,
                              hipStream_t stream){
  const float* features  = (const float*)d_in[0];
  const int*   captions  = (const int*)  d_in[1];
  const float* emb_table = (const float*)d_in[2];
  const float* ln_q_g = (const float*)d_in[3];
  const float* ln_q_b = (const float*)d_in[4];
  const float* ln_kv_g= (const float*)d_in[5];
  const float* ln_kv_b= (const float*)d_in[6];
  const float* Wq     = (const float*)d_in[7];
  const float* bq     = (const float*)d_in[8];
  const float* Wk     = (const float*)d_in[9];
  const float* bk     = (const float*)d_in[10];
  const float* Wbeta  = (const float*)d_in[11];
  const float* bbeta  = (const float*)d_in[12];
  const float* Wh     = (const float*)d_in[13];
  const float* Wu     = (const float*)d_in[14];
  const float* Wa     = (const float*)d_in[15];
  const float* b_gates= (const float*)d_in[16];
  const float* W_Lh   = (const float*)d_in[17];
  const float* b_Lh   = (const float*)d_in[18];
  const float* W_Lz   = (const float*)d_in[19];
  const float* b_Lz   = (const float*)d_in[20];
  const float* W_Lo   = (const float*)d_in[21];
  const float* b_Lo   = (const float*)d_in[22];
  const float* W_ih   = (const float*)d_in[23];
  const float* b_ih   = (const float*)d_in[24];
  const float* W_ic   = (const float*)d_in[25];
  const float* b_ic   = (const float*)d_in[26];

  float* pred = (float*)d_out;
  float* alph = pred + (size_t)NB * NTT * NV;

  char* w = (char*)d_ws;
  auto alloc = [&](size_t bytes) -> void* {
    void* p = (void*)w; w += (bytes + 255) & ~(size_t)255; return p;
  };
  unsigned short* feats_bf = (unsigned short*)alloc((size_t)NB*NP*DE * 2);
  unsigned short* wlo_t    = (unsigned short*)alloc((size_t)NV*KP * 2);
  unsigned short* whT      = (unsigned short*)alloc((size_t)G4*DD * 2);
  unsigned short* wut      = (unsigned short*)alloc((size_t)G4*KP * 2);
  unsigned short* wat      = (unsigned short*)alloc((size_t)G4*DE * 2);
  unsigned short* WkT      = (unsigned short*)alloc((size_t)DD*DE * 2);
  unsigned short* WLt      = (unsigned short*)alloc((size_t)KP*KG1 * 2);
  unsigned short* Wg       = (unsigned short*)alloc((size_t)DD*DD * 2);
  unsigned short* KFbf     = (unsigned short*)alloc((size_t)NB*NP*DD * 2);
  unsigned short* G2bf     = (unsigned short*)alloc((size_t)NB*NP*DD * 2);
  float2* sc12  = (float2*)alloc((size_t)NB*NP * 8);
  float* vq     = (float*)alloc((size_t)DD * 4);
  float* u_     = (float*)alloc((size_t)DD * 4);
  float* voff   = (float*)alloc((size_t)DD * 4);
  float* gw     = (float*)alloc((size_t)DD * 4);
  float* cscal  = (float*)alloc(16);
  float* mean_a = (float*)alloc((size_t)NB*DE * 4);
  float* hbuf   = (float*)alloc((size_t)NB*DD * 4);
  float* cb0    = (float*)alloc((size_t)NB*DD * 4);
  float* cb1    = (float*)alloc((size_t)NB*DD * 4);
  unsigned short* hstbf = (unsigned short*)alloc((size_t)(NS+1)*NB*DD * 2);
  unsigned short* zbf   = (unsigned short*)alloc((size_t)NS*NB*DE * 2);
  unsigned short* outo  = (unsigned short*)alloc((size_t)1920*KP * 2);
  unsigned short* gp    = (unsigned short*)alloc((size_t)KSPL*NB*G4 * 2);
  float* eu_all = (float*)alloc((size_t)NS*NB*G4 * 4);
  float* cb[2] = { cb0, cb1 };

  // pre-pass: 3 dispatches
  k_pre1<<<dim3(18169), dim3(512), 0, stream>>>(features, ln_kv_g, ln_kv_b,
      W_Lo, Wh, Wu, Wa, Wk, W_Lh, W_Lz, Wq, bk, ln_q_g, ln_q_b, bq, Wbeta,
      bbeta, pred, alph, feats_bf, mean_a, wlo_t, whT, wut, wat, WkT, WLt,
      Wg, vq, u_, voff, gw, cscal);
  k_pre2<<<dim3(1088), dim3(256), 0, stream>>>(feats_bf, WkT, mean_a,
      W_ih, b_ih, W_ic, b_ic, emb_table, captions, wut,
      KFbf, hbuf, hstbf, cb0, eu_all);
  k_pre3<<<dim3(2448), dim3(256), 0, stream>>>(KFbf, Wg, ln_q_g, vq,
      u_, voff, cscal, G2bf, sc12);

  for (int s = 0; s < NS; ++s){
    k_A<<<dim3(2, NB), dim3(512), 0, stream>>>(gp, eu_all, b_gates,
        cb[(s & 1) ^ 1], cb[s & 1], hstbf, G2bf, sc12, feats_bf,
        gw, cscal, s, 1, alph, zbf);
    k_B<<<dim3(32, KSPL), dim3(256), 0, stream>>>(hstbf, zbf, whT, wat, s, gp);
  }
  // final LSTM -> h_29
  k_A<<<dim3(1, NB), dim3(512), 0, stream>>>(gp, eu_all, b_gates,
      cb[(NS & 1) ^ 1], cb[NS & 1], hstbf, G2bf, sc12, feats_bf,
      gw, cscal, NS, 0, alph, zbf);

  // post-pass: 2 dispatches
  k_G1<<<dim3(15, 2), dim3(256), 0, stream>>>(hstbf, zbf, WLt, b_Lh, b_Lz,
      emb_table, captions, outo);
  k_G2<<<dim3(1875), dim3(256), 0, stream>>>(outo, wlo_t, b_Lo, pred);
}

// Round 12
// 1077.142 us; speedup vs baseline: 1.1468x; 1.1468x over previous
//
#include <hip/hip_runtime.h>
#include <hip/hip_bf16.h>

// Decoder (LSTM + attention captioner), MI355X. Round 24:
//  - r23 post-mortem: +93us NET. Counters isolated it: fused full-K k_G1 =
//    216us @ 1.05% occupancy (30 blocks, 36 serial kt) = +165us; pre-pass
//    3-dispatch fusion = -70us. Lesson: dispatch removal only pays if the
//    fused kernel keeps parallelism.
//  - r24: keep r23 pre-fusion (k_pre1/2/3); REVERT post to r22's split:
//    k_G1m (15,2,6)=180 blocks -> g1p partials, + k_G1red (sum + bias/emb
//    epilogue). Post = 3 dispatches, all parallel.

#define NB 64
#define NP 144
#define DE 1792
#define DD 512
#define DA 512
#define EM 300
#define NV 32000
#define NTT 30
#define NS 29
#define G4 2048
#define KP 320
#define KG1 2304
#define LN_EPS 1e-5f
#define RSCALE 0.044194173824159216f   // 1/sqrt(512)
#define KSPL 12       // K splits in k_B (2304 = 12 x 192)

typedef __attribute__((ext_vector_type(8))) short short8;
typedef __attribute__((ext_vector_type(4))) float f32x4;
typedef __attribute__((ext_vector_type(8))) unsigned short ushort8v;

__device__ __forceinline__ float bf2f(unsigned short u){
  union { unsigned int i; float f; } w; w.i = ((unsigned int)u) << 16; return w.f;
}
__device__ __forceinline__ unsigned short f2bf(float f){
  union { float f; unsigned int i; } u; u.f = f;
  unsigned int r = u.i + 0x7FFFu + ((u.i >> 16) & 1u);
  return (unsigned short)(r >> 16);
}
__device__ __forceinline__ float sigm(float x){ return 1.f/(1.f + __expf(-x)); }

__device__ __forceinline__ float wave_reduce_sum(float v){
  #pragma unroll
  for (int o = 32; o >= 1; o >>= 1) v += __shfl_xor(v, o);
  return v;
}
__device__ __forceinline__ float wave_reduce_max(float v){
  #pragma unroll
  for (int o = 32; o >= 1; o >>= 1) v = fmaxf(v, __shfl_xor(v, o));
  return v;
}
__device__ __forceinline__ float block_sum512(float v, float* sbuf8){
  v = wave_reduce_sum(v);
  const int lane = threadIdx.x & 63, wid = threadIdx.x >> 6;
  if (lane == 0) sbuf8[wid] = v;
  __syncthreads();
  float r = 0.f;
  #pragma unroll
  for (int i = 0; i < 8; ++i) r += sbuf8[i];
  __syncthreads();
  return r;
}

// ---- shared MFMA 64x64-tile helpers (validated r4..r10) ----
__device__ __forceinline__ void stage_tile(const unsigned short* __restrict__ src,
    int row_stride, int k0, char* lds){
  const int tid = threadIdx.x;
  #pragma unroll
  for (int c = 0; c < 2; ++c){
    const int o = tid + c*256;
    const int m = o >> 3, ks8 = o & 7;
    const ushort8v v = *(const ushort8v*)&src[(size_t)m*row_stride + k0 + ks8*8];
    *(ushort8v*)&lds[m*128 + ((ks8 ^ (m&7))<<4)] = v;
  }
}
__device__ __forceinline__ void mma64(const char* Alds, const char* Blds,
    int w, int lane, f32x4 acc[4]){
  #pragma unroll
  for (int ks = 0; ks < 2; ++ks){
    const int slot = ks*4 + (lane>>4);
    const int n = w*16 + (lane&15);
    const short8 bfv = *(const short8*)&Blds[n*128 + ((slot ^ (n&7))<<4)];
    #pragma unroll
    for (int fm = 0; fm < 4; ++fm){
      const int m = fm*16 + (lane&15);
      const short8 afv = *(const short8*)&Alds[m*128 + ((slot ^ (m&7))<<4)];
      acc[fm] = __builtin_amdgcn_mfma_f32_16x16x32_bf16(afv, bfv, acc[fm], 0, 0, 0);
    }
  }
}

// ---- big-tile GEMM body (k_G2-validated): 128M x 256N tile.
template <int NKT>
__device__ __forceinline__ void gemm_big(const unsigned short* __restrict__ A,
    const unsigned short* __restrict__ B, int sa, int sb,
    char* Alds, char* Blds, int mt, int nt, f32x4 acc[8][4]){
  const int tid = threadIdx.x, w = tid>>6, lane = tid&63;
  for (int kt = 0; kt < NKT; ++kt){
    const int k0 = kt*64;
    __syncthreads();
    #pragma unroll
    for (int c2 = 0; c2 < 4; ++c2){
      const int o16 = tid + c2*256;
      const int m = o16>>3, ks8 = o16&7;
      const ushort8v v = *(const ushort8v*)&A[(size_t)(mt*128+m)*sa + k0 + ks8*8];
      *(ushort8v*)&Alds[m*128 + ((ks8 ^ (m&7))<<4)] = v;
    }
    #pragma unroll
    for (int c2 = 0; c2 < 8; ++c2){
      const int o16 = tid + c2*256;
      const int n = o16>>3, ks8 = o16&7;
      const ushort8v v = *(const ushort8v*)&B[(size_t)(nt*256+n)*sb + k0 + ks8*8];
      *(ushort8v*)&Blds[n*128 + ((ks8 ^ (n&7))<<4)] = v;
    }
    __syncthreads();
    #pragma unroll
    for (int ks = 0; ks < 2; ++ks){
      const int slot = ks*4 + (lane>>4);
      short8 af[8];
      #pragma unroll
      for (int fm = 0; fm < 8; ++fm){
        const int m = fm*16 + (lane&15);
        af[fm] = *(const short8*)&Alds[m*128 + ((slot ^ (m&7))<<4)];
      }
      #pragma unroll
      for (int fn = 0; fn < 4; ++fn){
        const int n = w*64 + fn*16 + (lane&15);
        const short8 bfv = *(const short8*)&Blds[n*128 + ((slot ^ (n&7))<<4)];
        #pragma unroll
        for (int fm = 0; fm < 8; ++fm)
          acc[fm][fn] = __builtin_amdgcn_mfma_f32_16x16x32_bf16(af[fm], bfv, acc[fm][fn], 0, 0, 0);
      }
    }
  }
}

// ======== PRE stage 1: zero | ln_feats | mean | cvt_all | wg | prep.
// 512 threads. blocks: zero[0,4000) ln[4000,13216) mean[13216,13440)
// cvt[13440,17656) wg[17656,18168) prep[18168,18169).
__global__ __launch_bounds__(512) void k_pre1(
    const float* __restrict__ feats, const float* __restrict__ ln_kv_g,
    const float* __restrict__ ln_kv_b,
    const float* __restrict__ W_Lo, const float* __restrict__ Wh,
    const float* __restrict__ Wu,  const float* __restrict__ Wa,
    const float* __restrict__ Wk,  const float* __restrict__ W_Lh,
    const float* __restrict__ W_Lz,
    const float* __restrict__ Wq, const float* __restrict__ bk,
    const float* __restrict__ g,  const float* __restrict__ bln,
    const float* __restrict__ bq, const float* __restrict__ Wbeta,
    const float* __restrict__ bbeta,
    float* __restrict__ pred, float* __restrict__ alph,
    unsigned short* __restrict__ feats_bf, float* __restrict__ mean_a,
    unsigned short* __restrict__ wlo_t, unsigned short* __restrict__ whT,
    unsigned short* __restrict__ wut,   unsigned short* __restrict__ wat,
    unsigned short* __restrict__ WkT,   unsigned short* __restrict__ WLt,
    unsigned short* __restrict__ Wg, float* __restrict__ vq,
    float* __restrict__ u_, float* __restrict__ voff,
    float* __restrict__ gw, float* __restrict__ cscal){
  __shared__ float t[64][65];
  __shared__ float sbuf8[8];
  const int tid = threadIdx.x;
  int lb = blockIdx.x;
  if (lb < 4000){                       // ---- zero outputs
    const int idx = lb*512 + tid;
    { const int b = idx / NV, v = idx - b*NV;
      pred[(size_t)b*NTT*NV + v] = 0.f; }
    if (idx < NB*NP){
      const int b = idx / NP, p = idx - b*NP;
      alph[(size_t)b*NTT*NP + p] = 0.f; }
    return;
  }
  lb -= 4000;
  if (lb < 9216){                       // ---- LayerNorm(features) -> bf16
    const float* x = feats + (size_t)lb * DE;
    float v[4]; float s = 0.f;
    #pragma unroll
    for (int i = 0; i < 4; ++i){
      const int idx = i*512 + tid;
      v[i] = (idx < DE) ? x[idx] : 0.f;
      s += v[i];
    }
    const float mean = block_sum512(s, sbuf8) * (1.f/DE);
    float q = 0.f;
    #pragma unroll
    for (int i = 0; i < 4; ++i){
      const int idx = i*512 + tid;
      if (idx < DE){ const float d = v[i] - mean; q += d*d; }
    }
    const float var = block_sum512(q, sbuf8) * (1.f/DE);
    const float rinv = rsqrtf(var + LN_EPS);
    #pragma unroll
    for (int i = 0; i < 4; ++i){
      const int idx = i*512 + tid;
      if (idx < DE)
        feats_bf[(size_t)lb*DE + idx] = f2bf((v[i]-mean)*rinv*ln_kv_g[idx] + ln_kv_b[idx]);
    }
    return;
  }
  lb -= 9216;
  if (lb < 224){                        // ---- mean over patches
    const int idx = lb*512 + tid;
    const int b = idx / DE, d = idx - b*DE;
    const float* p = feats + (size_t)b*NP*DE + d;
    float s = 0.f;
    for (int pp = 0; pp < NP; ++pp) s += p[(size_t)pp*DE];
    mean_a[idx] = s * (1.f/NP);
    return;
  }
  lb -= 224;
  if (lb < 4216){                       // ---- all weight transposes
    if (lb >= 4036){
      int l2 = lb - 4036;
      const int e0 = (l2 % 5)*64, k0 = (l2 / 5)*64;
      for (int i = tid; i < 4096; i += 512){
        const int k = i>>6, e2 = i&63;
        const int kg = k0 + k, e = e0 + e2;
        float v = 0.f;
        if (e < EM) v = (kg < DD) ? W_Lh[(size_t)kg*EM + e] : W_Lz[(size_t)(kg-DD)*EM + e];
        t[k][e2] = v;
      }
      __syncthreads();
      for (int i = tid; i < 4096; i += 512){
        const int e2 = i>>6, k = i&63;
        WLt[(size_t)(e0+e2)*KG1 + k0+k] = f2bf(t[k][e2]);
      }
      return;
    }
    const float* src; unsigned short* dst; int K, N, KPad, nx;
    if      (lb < 2500){             src=W_Lo; dst=wlo_t; K=EM; N=NV; KPad=KP; nx=500; }
    else if (lb < 2756){ lb -= 2500; src=Wh;   dst=whT;   K=DD; N=G4; KPad=DD; nx=32; }
    else if (lb < 2916){ lb -= 2756; src=Wu;   dst=wut;   K=EM; N=G4; KPad=KP; nx=32; }
    else if (lb < 3812){ lb -= 2916; src=Wa;   dst=wat;   K=DE; N=G4; KPad=DE; nx=32; }
    else               { lb -= 3812; src=Wk;   dst=WkT;   K=DE; N=DD; KPad=DE; nx=8;  }
    const int n0 = (lb % nx)*64, k0 = (lb / nx)*64;
    for (int i = tid; i < 4096; i += 512){
      const int k = i>>6, n = i&63;
      t[k][n] = (k0 + k < K) ? src[(size_t)(k0+k)*N + n0+n] : 0.f;
    }
    __syncthreads();
    for (int i = tid; i < 4096; i += 512){
      const int n = i>>6, k = i&63;
      dst[(size_t)(n0+n)*KPad + k0+k] = f2bf(t[k][n]);
    }
    return;
  }
  lb -= 4216;
  if (lb < 512){                        // ---- Wg = diag(g) * Wq
    const int idx = lb*512 + tid;
    const int k = idx >> 9;
    Wg[idx] = f2bf(g[k]*Wq[idx]);
    return;
  }
  // ---- prep: vq + u/voff/gw/cscal (1 block)
  {
    const int a = tid;
    {
      const float* row = Wq + (size_t)a*DA;
      float acc = 0.f;
      for (int j = 0; j < DA; ++j) acc = fmaf(row[j], bk[j], acc);
      vq[a] = acc;
    }
    float uu = 0.f, vv = 0.f;
    for (int k = 0; k < DD; ++k){
      const float wv = Wq[(size_t)k*DA + a];
      uu = fmaf(g[k],   wv, uu);
      vv = fmaf(bln[k], wv, vv);
    }
    const float vo = vv + bq[a];
    u_[a]   = uu;
    voff[a] = vo;
    gw[a]   = g[a]*Wbeta[a];
    const float c1 = block_sum512(g[a]*Wbeta[a], sbuf8);
    const float c2 = block_sum512(bln[a]*Wbeta[a], sbuf8);
    const float c3 = block_sum512(uu*bk[a], sbuf8);
    const float c4 = block_sum512(vo*bk[a], sbuf8);
    if (a == 0){ cscal[0]=c1; cscal[1]=c2+bbeta[0]; cscal[2]=c3; cscal[3]=c4; }
  }
}

// ======== PRE stage 2: KF | init_g | EU.  256 threads.
// blocks: KF[0,144) (keeps bid%8 XCD map), init[144,160), EU[160,1088).
__global__ __launch_bounds__(256) void k_pre2(
    const unsigned short* __restrict__ fb, const unsigned short* __restrict__ WkT,
    const float* __restrict__ mean_a,
    const float* __restrict__ W_ih, const float* __restrict__ b_ih,
    const float* __restrict__ W_ic, const float* __restrict__ b_ic,
    const float* __restrict__ emb_table, const int* __restrict__ captions,
    const unsigned short* __restrict__ wut,
    unsigned short* __restrict__ KF, float* __restrict__ hbuf,
    unsigned short* __restrict__ hstbf, float* __restrict__ cb0,
    float* __restrict__ eu){
  __shared__ alignas(16) char smem[49152];
  const int tid = threadIdx.x, w = tid>>6, lane = tid&63;
  int lb = blockIdx.x;
  if (lb < 144){                        // ---- KF big-tile
    char* Alds = smem; char* Blds = smem + 16384;
    const int wgid = (lb & 7)*18 + (lb >> 3);
    const int nt = wgid & 1, mt = wgid >> 1;
    f32x4 acc[8][4];
    #pragma unroll
    for (int i = 0; i < 8; ++i)
      #pragma unroll
      for (int j = 0; j < 4; ++j) acc[i][j] = (f32x4)(0.f);
    gemm_big<28>(fb, WkT, DE, DE, Alds, Blds, mt, nt, acc);
    const int ncol0 = nt*256 + w*64 + (lane&15);
    #pragma unroll
    for (int fm = 0; fm < 8; ++fm)
      #pragma unroll
      for (int r = 0; r < 4; ++r){
        const int row = mt*128 + fm*16 + (lane>>4)*4 + r;
        #pragma unroll
        for (int fn = 0; fn < 4; ++fn)
          KF[(size_t)row*DD + ncol0 + fn*16] = f2bf(acc[fm][fn][r]);
      }
    return;
  }
  lb -= 144;
  if (lb < 16){                         // ---- h0/c0 GEMM
    float* la = (float*)smem;                 // 64*68 floats
    float* lw = (float*)smem + 64*68;
    const int which = lb >> 3;
    const float* W    = which ? W_ic : W_ih;
    const float* bias = which ? b_ic : b_ih;
    float* out = which ? cb0 : hbuf;
    unsigned short* outbf = which ? nullptr : hstbf;
    const int j0 = (lb & 7)*64;
    const int tr = tid&15, tn = tid>>4;
    float acc[16] = {0.f};
    for (int a0 = 0; a0 < DE; a0 += 64){
      __syncthreads();
      for (int i = tid; i < 4096; i += 256){
        const int b = i>>6, k = i&63;
        la[k*68 + b] = mean_a[(size_t)b*DE + a0+k];
      }
      for (int i = tid; i < 4096; i += 256){
        const int k = i>>6, j = i&63;
        lw[k*68 + j] = W[(size_t)(a0+k)*DD + j0+j];
      }
      __syncthreads();
      for (int k = 0; k < 64; ++k){
        float av[4], bv[4];
        #pragma unroll
        for (int ii = 0; ii < 4; ++ii) av[ii] = la[k*68 + tr*4+ii];
        #pragma unroll
        for (int jj = 0; jj < 4; ++jj) bv[jj] = lw[k*68 + tn*4+jj];
        #pragma unroll
        for (int ii = 0; ii < 4; ++ii)
          #pragma unroll
          for (int jj = 0; jj < 4; ++jj)
            acc[ii*4+jj] = fmaf(av[ii], bv[jj], acc[ii*4+jj]);
      }
    }
    #pragma unroll
    for (int ii = 0; ii < 4; ++ii)
      #pragma unroll
      for (int jj = 0; jj < 4; ++jj){
        const size_t idx = (size_t)(tr*4+ii)*DD + j0 + tn*4+jj;
        const float val = acc[ii*4+jj] + bias[j0 + tn*4+jj];
        out[idx] = val;
        if (outbf) outbf[idx] = f2bf(val);
      }
    return;
  }
  lb -= 16;
  {                                     // ---- EU: emb(s)@Wu
    char* Alds = smem; char* Blds = smem + 8192;
    int* capL = (int*)(smem + 16384);
    const int jt = lb & 31, s = lb >> 5;
    if (tid < 64) capL[tid] = captions[tid*NTT + s];
    f32x4 acc[4];
    #pragma unroll
    for (int i = 0; i < 4; ++i) acc[i] = (f32x4)(0.f);
    for (int kt = 0; kt < 5; ++kt){
      __syncthreads();
      #pragma unroll
      for (int c = 0; c < 2; ++c){
        const int o = tid + c*256;
        const int m = o>>3, ks8 = o&7;
        const int e0 = kt*64 + ks8*8;
        const float* er = emb_table + (size_t)capL[m]*EM;
        ushort8v v;
        #pragma unroll
        for (int jj = 0; jj < 8; ++jj)
          v[jj] = (e0 + jj < EM) ? f2bf(er[e0 + jj]) : (unsigned short)0;
        *(ushort8v*)&Alds[m*128 + ((ks8 ^ (m&7))<<4)] = v;
      }
      stage_tile(wut + (size_t)jt*64*KP, KP, kt*64, Blds);
      __syncthreads();
      mma64(Alds, Blds, w, lane, acc);
    }
    const int j = jt*64 + w*16 + (lane&15);
    #pragma unroll
    for (int fm = 0; fm < 4; ++fm)
      #pragma unroll
      for (int r = 0; r < 4; ++r){
        const int b = fm*16 + (lane>>4)*4 + r;
        eu[((size_t)s*NB + b)*G4 + j] = acc[fm][r];
      }
  }
}

// ======== PRE stage 3: QG2 | sc12.  256 threads.
// blocks: QG2[0,144), sc12[144,2448) (4 rows/block, wave-level).
__global__ __launch_bounds__(256) void k_pre3(
    const unsigned short* __restrict__ KF, const unsigned short* __restrict__ Wg,
    const float* __restrict__ g_, const float* __restrict__ vq,
    const float* __restrict__ u_, const float* __restrict__ voff,
    const float* __restrict__ cscal,
    unsigned short* __restrict__ G2, float2* __restrict__ sc12){
  __shared__ alignas(16) char smem[49152];
  const int tid = threadIdx.x, w = tid>>6, lane = tid&63;
  int lb = blockIdx.x;
  if (lb < 144){                        // ---- G2 big-tile
    char* Alds = smem; char* Blds = smem + 16384;
    const int wgid = (lb & 7)*18 + (lb >> 3);
    const int nt = wgid & 1, mt = wgid >> 1;
    f32x4 acc[8][4];
    #pragma unroll
    for (int i = 0; i < 8; ++i)
      #pragma unroll
      for (int j = 0; j < 4; ++j) acc[i][j] = (f32x4)(0.f);
    gemm_big<8>(KF, Wg, DD, DD, Alds, Blds, mt, nt, acc);
    const int ncol0 = nt*256 + w*64 + (lane&15);
    float addv[4];
    #pragma unroll
    for (int fn = 0; fn < 4; ++fn){
      const int q = ncol0 + fn*16;
      addv[fn] = g_[q]*vq[q];
    }
    #pragma unroll
    for (int fm = 0; fm < 8; ++fm)
      #pragma unroll
      for (int r = 0; r < 4; ++r){
        const int row = mt*128 + fm*16 + (lane>>4)*4 + r;
        #pragma unroll
        for (int fn = 0; fn < 4; ++fn)
          G2[(size_t)row*DD + ncol0 + fn*16] = f2bf(acc[fm][fn][r] + addv[fn]);
      }
    return;
  }
  lb -= 144;
  {                                     // ---- sc12, 4 rows/block
    const int row = lb*4 + w;
    const unsigned short* kf = KF + (size_t)row*DD + lane*8;
    float s1 = 0.f, s2 = 0.f;
    #pragma unroll
    for (int j = 0; j < 8; ++j){
      const float kv = bf2f(kf[j]);
      s1 = fmaf(u_[lane*8 + j],   kv, s1);
      s2 = fmaf(voff[lane*8 + j], kv, s2);
    }
    s1 = wave_reduce_sum(s1);
    s2 = wave_reduce_sum(s2);
    if (lane == 0){
      float2 o; o.x = s1 + cscal[2]; o.y = s2 + cscal[3];
      sc12[row] = o;
    }
  }
}

// ======== per-step kernel A (r21 structure; gp bf16)
__global__ __launch_bounds__(512) void k_A(
    const unsigned short* __restrict__ gp, const float* __restrict__ eu,
    const float* __restrict__ b_gates, const float* __restrict__ cin,
    float* __restrict__ cout, unsigned short* __restrict__ hst,
    const unsigned short* __restrict__ G2, const float2* __restrict__ sc12,
    const unsigned short* __restrict__ fb, const float* __restrict__ gw,
    const float* __restrict__ cscal, const int s, const int do_att,
    float* __restrict__ alph, unsigned short* __restrict__ zbf){
  __shared__ alignas(16) unsigned short hL[DD];
  __shared__ float sc[NP];
  __shared__ float al[NP];
  __shared__ float sredA[8*4];
  __shared__ float sbufM[8];
  __shared__ float sbufS[8];
  int sl, b;
  if (gridDim.x == 1){ sl = 0; b = blockIdx.y; }
  else {
    const int lin = blockIdx.x + 2*blockIdx.y;
    const int xcd = lin & 7, i = lin >> 3;
    b = xcd*8 + (i & 7);
    sl = i >> 3;
  }
  const int tid = threadIdx.x;
  const int w = tid>>6, lane = tid&63;
  float hn;
  if (s == 0){
    const unsigned short hb = hst[(size_t)b*DD + tid];
    hn = bf2f(hb);
    hL[tid] = hb;
  } else {
    const int m = s - 1;
    unsigned short gv[4*KSPL];
    #pragma unroll
    for (int ks = 0; ks < KSPL; ++ks){
      const unsigned short* gr = gp + ((size_t)ks*NB + b)*G4 + tid;
      gv[ks*4+0] = gr[0];
      gv[ks*4+1] = gr[DD];
      gv[ks*4+2] = gr[2*DD];
      gv[ks*4+3] = gr[3*DD];
    }
    const float* eur = eu + ((size_t)m*NB + b)*G4 + tid;
    float gs0 = b_gates[tid]        + eur[0];
    float gs1 = b_gates[DD + tid]   + eur[DD];
    float gs2 = b_gates[2*DD + tid] + eur[2*DD];
    float gs3 = b_gates[3*DD + tid] + eur[3*DD];
    #pragma unroll
    for (int ks = 0; ks < KSPL; ++ks){
      gs0 += bf2f(gv[ks*4+0]); gs1 += bf2f(gv[ks*4+1]);
      gs2 += bf2f(gv[ks*4+2]); gs3 += bf2f(gv[ks*4+3]);
    }
    const size_t idx = (size_t)b*DD + tid;
    const float cn = sigm(gs1)*cin[idx] + sigm(gs0)*tanhf(gs3);
    hn = sigm(gs2)*tanhf(cn);
    cout[idx] = cn;
    const unsigned short hb = f2bf(hn);
    hst[(size_t)s*NB*DD + idx] = hb;
    hL[tid] = hb;
  }
  if (!do_att) return;
  float p1 = hn, p2 = hn*hn, p3 = hn*gw[tid];
  #pragma unroll
  for (int o = 32; o >= 1; o >>= 1){
    p1 += __shfl_xor(p1, o);
    p2 += __shfl_xor(p2, o);
    p3 += __shfl_xor(p3, o);
  }
  if (lane == 0){ sredA[w*4] = p1; sredA[w*4+1] = p2; sredA[w*4+2] = p3; }
  __syncthreads();
  float S1 = 0.f, S2 = 0.f, S3 = 0.f;
  #pragma unroll
  for (int i = 0; i < 8; ++i){
    S1 += sredA[i*4]; S2 += sredA[i*4+1]; S3 += sredA[i*4+2];
  }
  const float mean = S1*(1.f/512.f);
  const float var  = S2*(1.f/512.f) - mean*mean;
  const float rinv = rsqrtf(var + LN_EPS);
  const float beta = sigm(rinv*(S3 - mean*cscal[0]) + cscal[1]);
  const short8 hv = *(const short8*)&hL[lane*8];
  #pragma unroll 1
  for (int i0 = 0; i0 < 18; i0 += 9){
    short8 U[9];
    float2 SV[9];
    #pragma unroll
    for (int j = 0; j < 9; ++j){
      const int p = w + 8*(i0+j);
      U[j] = *(const short8*)&G2[(size_t)(b*NP + p)*DD + lane*8];
      if (lane == 0) SV[j] = sc12[b*NP + p];
    }
    #pragma unroll
    for (int j = 0; j < 9; ++j){
      float a2 = 0.f;
      #pragma unroll
      for (int q = 0; q < 8; ++q)
        a2 = fmaf(bf2f((unsigned short)U[j][q]), bf2f((unsigned short)hv[q]), a2);
      a2 = wave_reduce_sum(a2);
      if (lane == 0)
        sc[w + 8*(i0+j)] = RSCALE*(rinv*a2 - rinv*mean*SV[j].x + SV[j].y);
    }
  }
  __syncthreads();
  const float v = (tid < NP) ? sc[tid] : -1e30f;
  const float mv = wave_reduce_max(v);
  if (lane == 0) sbufM[w] = mv;
  __syncthreads();
  float mm = sbufM[0];
  #pragma unroll
  for (int i = 1; i < 8; ++i) mm = fmaxf(mm, sbufM[i]);
  const float e = (tid < NP) ? __expf(v - mm) : 0.f;
  const float sv = wave_reduce_sum(e);
  if (lane == 0) sbufS[w] = sv;
  __syncthreads();
  float ssum = 0.f;
  #pragma unroll
  for (int i = 0; i < 8; ++i) ssum += sbufS[i];
  if (tid < NP){
    const float a3 = e / ssum;
    al[tid] = a3;
    if (sl == 0) alph[((size_t)b*NTT + s + 1)*NP + tid] = a3;
  }
  __syncthreads();
  if (tid < 448){
    const int d0 = sl*896 + tid*2;
    const unsigned short* fB = fb + (size_t)b*NP*DE + d0;
    float a0 = 0.f, a1 = 0.f;
    #pragma unroll 1
    for (int p0 = 0; p0 < NP; p0 += 36){
      ushort2 fv[36];
      #pragma unroll
      for (int j = 0; j < 36; ++j) fv[j] = *(const ushort2*)&fB[(size_t)(p0+j)*DE];
      #pragma unroll
      for (int j = 0; j < 36; ++j){
        const float ap = al[p0+j];
        a0 = fmaf(ap, bf2f(fv[j].x), a0);
        a1 = fmaf(ap, bf2f(fv[j].y), a1);
      }
    }
    ushort2 zo;
    zo.x = f2bf(a0*beta);
    zo.y = f2bf(a1*beta);
    *(ushort2*)&zbf[((size_t)s*NB + b)*DE + d0] = zo;
  }
}

// ======== per-step kernel B (K-split 12, bf16 gp out).  grid (32, 12).
__global__ __launch_bounds__(256) void k_B(
    const unsigned short* __restrict__ hst, const unsigned short* __restrict__ zbf,
    const unsigned short* __restrict__ whT, const unsigned short* __restrict__ wat,
    const int s, unsigned short* __restrict__ gp){
  __shared__ char Alds[8192];
  __shared__ char Blds[8192];
  const int jt = blockIdx.x, ks = blockIdx.y;
  const int tid = threadIdx.x, w = tid>>6, lane = tid&63;
  const unsigned short* hrow = hst + (size_t)s*NB*DD;
  const unsigned short* zrow = zbf + (size_t)s*NB*DE;
  f32x4 acc[4];
  #pragma unroll
  for (int i = 0; i < 4; ++i) acc[i] = (f32x4)(0.f);
  for (int kt = 0; kt < 3; ++kt){
    const int k0 = ks*192 + kt*64;
    __syncthreads();
    if (k0 < DD) stage_tile(hrow, DD, k0, Alds);
    else         stage_tile(zrow, DE, k0 - DD, Alds);
    #pragma unroll
    for (int c2 = 0; c2 < 2; ++c2){
      const int o = tid + c2*256;
      const int m = o>>3, ks8 = o&7;
      const int col = (m>>4)*DD + jt*16 + (m&15);
      const unsigned short* src = (k0 < DD)
          ? whT + (size_t)col*DD + k0
          : wat + (size_t)col*DE + (k0 - DD);
      const ushort8v v = *(const ushort8v*)&src[ks8*8];
      *(ushort8v*)&Blds[m*128 + ((ks8 ^ (m&7))<<4)] = v;
    }
    __syncthreads();
    mma64(Alds, Blds, w, lane, acc);
  }
  const int jcol = jt*16 + (lane&15);
  unsigned short* gps = gp + (size_t)ks*NB*G4;
  #pragma unroll
  for (int fm = 0; fm < 4; ++fm)
    #pragma unroll
    for (int r = 0; r < 4; ++r){
      const int b = fm*16 + (lane>>4)*4 + r;
      gps[(size_t)b*G4 + w*DD + jcol] = f2bf(acc[fm][r]);
    }
}

// ---- post G1m: out_o partial, BIG-TILE.  grid (15 mt, 2 nt, 6 ksplit).
// M = NS*NB = 1856 (row guard), N = KP = 320 (col guard, B-row clamp).
__global__ __launch_bounds__(256) void k_G1m(const unsigned short* __restrict__ hstbf,
    const unsigned short* __restrict__ zbf, const unsigned short* __restrict__ WLt,
    float* __restrict__ g1p){
  __shared__ char Alds[128*128];
  __shared__ char Blds[256*128];
  const int mt = blockIdx.x, nt = blockIdx.y, ks6 = blockIdx.z;
  const int tid = threadIdx.x, w = tid>>6, lane = tid&63;
  f32x4 acc[8][4];
  #pragma unroll
  for (int i = 0; i < 8; ++i)
    #pragma unroll
    for (int j = 0; j < 4; ++j) acc[i][j] = (f32x4)(0.f);
  for (int kt = 0; kt < 6; ++kt){
    const int k0 = ks6*384 + kt*64;       // 64-aligned; never straddles DD
    __syncthreads();
    #pragma unroll
    for (int c2 = 0; c2 < 4; ++c2){
      const int o16 = tid + c2*256;
      const int m = o16>>3, ks8 = o16&7;
      const int r = mt*128 + m;
      ushort8v v;
      if (r < NS*NB){
        const int sS = r >> 6, bb = r & 63;
        const unsigned short* srcp = (k0 < DD)
            ? hstbf + ((size_t)(sS+1)*NB + bb)*DD + k0
            : zbf + ((size_t)sS*NB + bb)*DE + (k0 - DD);
        v = *(const ushort8v*)&srcp[ks8*8];
      } else {
        #pragma unroll
        for (int j = 0; j < 8; ++j) v[j] = 0;
      }
      *(ushort8v*)&Alds[m*128 + ((ks8 ^ (m&7))<<4)] = v;
    }
    #pragma unroll
    for (int c2 = 0; c2 < 8; ++c2){
      const int o16 = tid + c2*256;
      const int n = o16>>3, ks8 = o16&7;
      int nr = nt*256 + n;
      if (nr >= KP) nr = KP - 1;          // clamp (results discarded by guard)
      const ushort8v v = *(const ushort8v*)&WLt[(size_t)nr*KG1 + k0 + ks8*8];
      *(ushort8v*)&Blds[n*128 + ((ks8 ^ (n&7))<<4)] = v;
    }
    __syncthreads();
    #pragma unroll
    for (int ks = 0; ks < 2; ++ks){
      const int slot = ks*4 + (lane>>4);
      short8 af[8];
      #pragma unroll
      for (int fm = 0; fm < 8; ++fm){
        const int m = fm*16 + (lane&15);
        af[fm] = *(const short8*)&Alds[m*128 + ((slot ^ (m&7))<<4)];
      }
      #pragma unroll
      for (int fn = 0; fn < 4; ++fn){
        const int n = w*64 + fn*16 + (lane&15);
        const short8 bfv = *(const short8*)&Blds[n*128 + ((slot ^ (n&7))<<4)];
        #pragma unroll
        for (int fm = 0; fm < 8; ++fm)
          acc[fm][fn] = __builtin_amdgcn_mfma_f32_16x16x32_bf16(af[fm], bfv, acc[fm][fn], 0, 0, 0);
      }
    }
  }
  const int ncol0 = nt*256 + w*64 + (lane&15);
  float* dst = g1p + (size_t)ks6*NS*NB*KP;
  #pragma unroll
  for (int fm = 0; fm < 8; ++fm){
    #pragma unroll
    for (int r = 0; r < 4; ++r){
      const int row = mt*128 + fm*16 + (lane>>4)*4 + r;
      if (row < NS*NB){
        #pragma unroll
        for (int fn = 0; fn < 4; ++fn){
          const int e = ncol0 + fn*16;
          if (e < KP) dst[(size_t)row*KP + e] = acc[fm][fn][r];
        }
      }
    }
  }
}

// ---- post G1red: sum 6 partials + emb + biases -> outo bf16
__global__ __launch_bounds__(256) void k_G1red(const float* __restrict__ g1p,
    const float* __restrict__ b_Lh, const float* __restrict__ b_Lz,
    const float* __restrict__ emb_table, const int* __restrict__ captions,
    unsigned short* __restrict__ outo){
  const int idx = blockIdx.x*256 + threadIdx.x;
  const int row = idx / KP, e = idx - row*KP;
  const int s = row >> 6, b = row & 63;
  float v = 0.f;
  #pragma unroll
  for (int ks6 = 0; ks6 < 6; ++ks6) v += g1p[(size_t)ks6*NS*NB*KP + idx];
  if (e < EM){
    const int cap = captions[b*NTT + s];
    v += b_Lh[e] + b_Lz[e] + emb_table[(size_t)cap*EM + e];
  } else v = 0.f;
  outo[idx] = f2bf(v);
}

// ---- post G2: logits MFMA, M-tile 128.  1D grid 1875, bijective XCD
// swizzle (r18).  NONTEMPORAL stores.
__global__ __launch_bounds__(256) void k_G2(const unsigned short* __restrict__ Abf,
    const unsigned short* __restrict__ Bt, const float* __restrict__ b_Lo,
    float* __restrict__ pred){
  __shared__ char Alds[128*128];
  __shared__ char Blds[256*128];
  const int bid = blockIdx.x;
  const int xcd = bid & 7, idx8 = bid >> 3;
  const int wgid = (xcd < 3 ? xcd*235 : 705 + (xcd-3)*234) + idx8;
  const int nt = wgid / 15, mt = wgid - nt*15;
  const int tid = threadIdx.x, w = tid>>6, lane = tid&63;
  f32x4 acc[8][4];
  #pragma unroll
  for (int i = 0; i < 8; ++i)
    #pragma unroll
    for (int j = 0; j < 4; ++j)
      acc[i][j] = (f32x4)(0.f);
  gemm_big<5>(Abf, Bt, KP, KP, Alds, Blds, mt, nt, acc);
  const int ncol0 = nt*256 + w*64 + (lane&15);
  #pragma unroll
  for (int fm = 0; fm < 8; ++fm){
    #pragma unroll
    for (int r = 0; r < 4; ++r){
      const int row = mt*128 + fm*16 + (lane>>4)*4 + r;
      if (row < NS*NB){
        const int s = row >> 6, b = row & 63;
        float* prow = &pred[((size_t)b*NTT + s + 1)*NV + ncol0];
        #pragma unroll
        for (int fn = 0; fn < 4; ++fn)
          __builtin_nontemporal_store(acc[fm][fn][r] + b_Lo[ncol0 + fn*16],
                                      &prow[fn*16]);
      }
    }
  }
}

extern "C" void kernel_launch(void* const* d_in, const int* in_sizes, int n_in,
                              void* d_out, int out_size, void* d_ws, size_t ws_size,
                              hipStream_t stream){
  const float* features  = (const float*)d_in[0];
  const int*   captions  = (const int*)  d_in[1];
  const float* emb_table = (const float*)d_in[2];
  const float* ln_q_g = (const float*)d_in[3];
  const float* ln_q_b = (const float*)d_in[4];
  const float* ln_kv_g= (const float*)d_in[5];
  const float* ln_kv_b= (const float*)d_in[6];
  const float* Wq     = (const float*)d_in[7];
  const float* bq     = (const float*)d_in[8];
  const float* Wk     = (const float*)d_in[9];
  const float* bk     = (const float*)d_in[10];
  const float* Wbeta  = (const float*)d_in[11];
  const float* bbeta  = (const float*)d_in[12];
  const float* Wh     = (const float*)d_in[13];
  const float* Wu     = (const float*)d_in[14];
  const float* Wa     = (const float*)d_in[15];
  const float* b_gates= (const float*)d_in[16];
  const float* W_Lh   = (const float*)d_in[17];
  const float* b_Lh   = (const float*)d_in[18];
  const float* W_Lz   = (const float*)d_in[19];
  const float* b_Lz   = (const float*)d_in[20];
  const float* W_Lo   = (const float*)d_in[21];
  const float* b_Lo   = (const float*)d_in[22];
  const float* W_ih   = (const float*)d_in[23];
  const float* b_ih   = (const float*)d_in[24];
  const float* W_ic   = (const float*)d_in[25];
  const float* b_ic   = (const float*)d_in[26];

  float* pred = (float*)d_out;
  float* alph = pred + (size_t)NB * NTT * NV;

  char* w = (char*)d_ws;
  auto alloc = [&](size_t bytes) -> void* {
    void* p = (void*)w; w += (bytes + 255) & ~(size_t)255; return p;
  };
  unsigned short* feats_bf = (unsigned short*)alloc((size_t)NB*NP*DE * 2);
  unsigned short* wlo_t    = (unsigned short*)alloc((size_t)NV*KP * 2);
  unsigned short* whT      = (unsigned short*)alloc((size_t)G4*DD * 2);
  unsigned short* wut      = (unsigned short*)alloc((size_t)G4*KP * 2);
  unsigned short* wat      = (unsigned short*)alloc((size_t)G4*DE * 2);
  unsigned short* WkT      = (unsigned short*)alloc((size_t)DD*DE * 2);
  unsigned short* WLt      = (unsigned short*)alloc((size_t)KP*KG1 * 2);
  unsigned short* Wg       = (unsigned short*)alloc((size_t)DD*DD * 2);
  unsigned short* KFbf     = (unsigned short*)alloc((size_t)NB*NP*DD * 2);
  unsigned short* G2bf     = (unsigned short*)alloc((size_t)NB*NP*DD * 2);
  float2* sc12  = (float2*)alloc((size_t)NB*NP * 8);
  float* vq     = (float*)alloc((size_t)DD * 4);
  float* u_     = (float*)alloc((size_t)DD * 4);
  float* voff   = (float*)alloc((size_t)DD * 4);
  float* gw     = (float*)alloc((size_t)DD * 4);
  float* cscal  = (float*)alloc(16);
  float* mean_a = (float*)alloc((size_t)NB*DE * 4);
  float* hbuf   = (float*)alloc((size_t)NB*DD * 4);
  float* cb0    = (float*)alloc((size_t)NB*DD * 4);
  float* cb1    = (float*)alloc((size_t)NB*DD * 4);
  unsigned short* hstbf = (unsigned short*)alloc((size_t)(NS+1)*NB*DD * 2);
  unsigned short* zbf   = (unsigned short*)alloc((size_t)NS*NB*DE * 2);
  unsigned short* outo  = (unsigned short*)alloc((size_t)1920*KP * 2);
  unsigned short* gp    = (unsigned short*)alloc((size_t)KSPL*NB*G4 * 2);
  float* eu_all = (float*)alloc((size_t)NS*NB*G4 * 4);
  float* g1p    = (float*)alloc((size_t)6*NS*NB*KP * 4);
  float* cb[2] = { cb0, cb1 };

  // pre-pass: 3 dispatches
  k_pre1<<<dim3(18169), dim3(512), 0, stream>>>(features, ln_kv_g, ln_kv_b,
      W_Lo, Wh, Wu, Wa, Wk, W_Lh, W_Lz, Wq, bk, ln_q_g, ln_q_b, bq, Wbeta,
      bbeta, pred, alph, feats_bf, mean_a, wlo_t, whT, wut, wat, WkT, WLt,
      Wg, vq, u_, voff, gw, cscal);
  k_pre2<<<dim3(1088), dim3(256), 0, stream>>>(feats_bf, WkT, mean_a,
      W_ih, b_ih, W_ic, b_ic, emb_table, captions, wut,
      KFbf, hbuf, hstbf, cb0, eu_all);
  k_pre3<<<dim3(2448), dim3(256), 0, stream>>>(KFbf, Wg, ln_q_g, vq,
      u_, voff, cscal, G2bf, sc12);

  for (int s = 0; s < NS; ++s){
    k_A<<<dim3(2, NB), dim3(512), 0, stream>>>(gp, eu_all, b_gates,
        cb[(s & 1) ^ 1], cb[s & 1], hstbf, G2bf, sc12, feats_bf,
        gw, cscal, s, 1, alph, zbf);
    k_B<<<dim3(32, KSPL), dim3(256), 0, stream>>>(hstbf, zbf, whT, wat, s, gp);
  }
  // final LSTM -> h_29
  k_A<<<dim3(1, NB), dim3(512), 0, stream>>>(gp, eu_all, b_gates,
      cb[(NS & 1) ^ 1], cb[NS & 1], hstbf, G2bf, sc12, feats_bf,
      gw, cscal, NS, 0, alph, zbf);

  // post-pass: 3 dispatches (r22-proven split)
  k_G1m<<<dim3(15, 2, 6), dim3(256), 0, stream>>>(hstbf, zbf, WLt, g1p);
  k_G1red<<<dim3((NS*NB*KP)/256), dim3(256), 0, stream>>>(g1p, b_Lh, b_Lz,
      emb_table, captions, outo);
  k_G2<<<dim3(1875), dim3(256), 0, stream>>>(outo, wlo_t, b_Lo, pred);
}

// Round 13
// 1054.319 us; speedup vs baseline: 1.1716x; 1.0216x over previous
//
#include <hip/hip_runtime.h>
#include <hip/hip_bf16.h>

// Decoder (LSTM + attention captioner), MI355X. Round 25:
//  - r24 post-mortem: 1235.2 -> 1077.1 (matched; pre-fusion + parallel post
//    split). Top-5 all harness fills. Loop ~31us/step dominates (~900us).
//  - r25 SINGLE CHANGE: k_A 2 -> 4 slices/batch (grid (4,NB)=256 blocks,
//    1/CU; was 0.5/CU). r19's "2 slices won" was confounded with load-width
//    changes; r20 proved loop is NOT BW-bound, so the +16MB/step of
//    score/gp redundancy is cheap and the 2x parallelism on the z/scores
//    phases should pay. z-GEMV: 1 col/thread (448/block, ushort loads,
//    same 36-deep batching).

#define NB 64
#define NP 144
#define DE 1792
#define DD 512
#define DA 512
#define EM 300
#define NV 32000
#define NTT 30
#define NS 29
#define G4 2048
#define KP 320
#define KG1 2304
#define LN_EPS 1e-5f
#define RSCALE 0.044194173824159216f   // 1/sqrt(512)
#define KSPL 12       // K splits in k_B (2304 = 12 x 192)

typedef __attribute__((ext_vector_type(8))) short short8;
typedef __attribute__((ext_vector_type(4))) float f32x4;
typedef __attribute__((ext_vector_type(8))) unsigned short ushort8v;

__device__ __forceinline__ float bf2f(unsigned short u){
  union { unsigned int i; float f; } w; w.i = ((unsigned int)u) << 16; return w.f;
}
__device__ __forceinline__ unsigned short f2bf(float f){
  union { float f; unsigned int i; } u; u.f = f;
  unsigned int r = u.i + 0x7FFFu + ((u.i >> 16) & 1u);
  return (unsigned short)(r >> 16);
}
__device__ __forceinline__ float sigm(float x){ return 1.f/(1.f + __expf(-x)); }

__device__ __forceinline__ float wave_reduce_sum(float v){
  #pragma unroll
  for (int o = 32; o >= 1; o >>= 1) v += __shfl_xor(v, o);
  return v;
}
__device__ __forceinline__ float wave_reduce_max(float v){
  #pragma unroll
  for (int o = 32; o >= 1; o >>= 1) v = fmaxf(v, __shfl_xor(v, o));
  return v;
}
__device__ __forceinline__ float block_sum512(float v, float* sbuf8){
  v = wave_reduce_sum(v);
  const int lane = threadIdx.x & 63, wid = threadIdx.x >> 6;
  if (lane == 0) sbuf8[wid] = v;
  __syncthreads();
  float r = 0.f;
  #pragma unroll
  for (int i = 0; i < 8; ++i) r += sbuf8[i];
  __syncthreads();
  return r;
}

// ---- shared MFMA 64x64-tile helpers (validated r4..r10) ----
__device__ __forceinline__ void stage_tile(const unsigned short* __restrict__ src,
    int row_stride, int k0, char* lds){
  const int tid = threadIdx.x;
  #pragma unroll
  for (int c = 0; c < 2; ++c){
    const int o = tid + c*256;
    const int m = o >> 3, ks8 = o & 7;
    const ushort8v v = *(const ushort8v*)&src[(size_t)m*row_stride + k0 + ks8*8];
    *(ushort8v*)&lds[m*128 + ((ks8 ^ (m&7))<<4)] = v;
  }
}
__device__ __forceinline__ void mma64(const char* Alds, const char* Blds,
    int w, int lane, f32x4 acc[4]){
  #pragma unroll
  for (int ks = 0; ks < 2; ++ks){
    const int slot = ks*4 + (lane>>4);
    const int n = w*16 + (lane&15);
    const short8 bfv = *(const short8*)&Blds[n*128 + ((slot ^ (n&7))<<4)];
    #pragma unroll
    for (int fm = 0; fm < 4; ++fm){
      const int m = fm*16 + (lane&15);
      const short8 afv = *(const short8*)&Alds[m*128 + ((slot ^ (m&7))<<4)];
      acc[fm] = __builtin_amdgcn_mfma_f32_16x16x32_bf16(afv, bfv, acc[fm], 0, 0, 0);
    }
  }
}

// ---- big-tile GEMM body (k_G2-validated): 128M x 256N tile.
template <int NKT>
__device__ __forceinline__ void gemm_big(const unsigned short* __restrict__ A,
    const unsigned short* __restrict__ B, int sa, int sb,
    char* Alds, char* Blds, int mt, int nt, f32x4 acc[8][4]){
  const int tid = threadIdx.x, w = tid>>6, lane = tid&63;
  for (int kt = 0; kt < NKT; ++kt){
    const int k0 = kt*64;
    __syncthreads();
    #pragma unroll
    for (int c2 = 0; c2 < 4; ++c2){
      const int o16 = tid + c2*256;
      const int m = o16>>3, ks8 = o16&7;
      const ushort8v v = *(const ushort8v*)&A[(size_t)(mt*128+m)*sa + k0 + ks8*8];
      *(ushort8v*)&Alds[m*128 + ((ks8 ^ (m&7))<<4)] = v;
    }
    #pragma unroll
    for (int c2 = 0; c2 < 8; ++c2){
      const int o16 = tid + c2*256;
      const int n = o16>>3, ks8 = o16&7;
      const ushort8v v = *(const ushort8v*)&B[(size_t)(nt*256+n)*sb + k0 + ks8*8];
      *(ushort8v*)&Blds[n*128 + ((ks8 ^ (n&7))<<4)] = v;
    }
    __syncthreads();
    #pragma unroll
    for (int ks = 0; ks < 2; ++ks){
      const int slot = ks*4 + (lane>>4);
      short8 af[8];
      #pragma unroll
      for (int fm = 0; fm < 8; ++fm){
        const int m = fm*16 + (lane&15);
        af[fm] = *(const short8*)&Alds[m*128 + ((slot ^ (m&7))<<4)];
      }
      #pragma unroll
      for (int fn = 0; fn < 4; ++fn){
        const int n = w*64 + fn*16 + (lane&15);
        const short8 bfv = *(const short8*)&Blds[n*128 + ((slot ^ (n&7))<<4)];
        #pragma unroll
        for (int fm = 0; fm < 8; ++fm)
          acc[fm][fn] = __builtin_amdgcn_mfma_f32_16x16x32_bf16(af[fm], bfv, acc[fm][fn], 0, 0, 0);
      }
    }
  }
}

// ======== PRE stage 1: zero | ln_feats | mean | cvt_all | wg | prep.
// 512 threads. blocks: zero[0,4000) ln[4000,13216) mean[13216,13440)
// cvt[13440,17656) wg[17656,18168) prep[18168,18169).
__global__ __launch_bounds__(512) void k_pre1(
    const float* __restrict__ feats, const float* __restrict__ ln_kv_g,
    const float* __restrict__ ln_kv_b,
    const float* __restrict__ W_Lo, const float* __restrict__ Wh,
    const float* __restrict__ Wu,  const float* __restrict__ Wa,
    const float* __restrict__ Wk,  const float* __restrict__ W_Lh,
    const float* __restrict__ W_Lz,
    const float* __restrict__ Wq, const float* __restrict__ bk,
    const float* __restrict__ g,  const float* __restrict__ bln,
    const float* __restrict__ bq, const float* __restrict__ Wbeta,
    const float* __restrict__ bbeta,
    float* __restrict__ pred, float* __restrict__ alph,
    unsigned short* __restrict__ feats_bf, float* __restrict__ mean_a,
    unsigned short* __restrict__ wlo_t, unsigned short* __restrict__ whT,
    unsigned short* __restrict__ wut,   unsigned short* __restrict__ wat,
    unsigned short* __restrict__ WkT,   unsigned short* __restrict__ WLt,
    unsigned short* __restrict__ Wg, float* __restrict__ vq,
    float* __restrict__ u_, float* __restrict__ voff,
    float* __restrict__ gw, float* __restrict__ cscal){
  __shared__ float t[64][65];
  __shared__ float sbuf8[8];
  const int tid = threadIdx.x;
  int lb = blockIdx.x;
  if (lb < 4000){                       // ---- zero outputs
    const int idx = lb*512 + tid;
    { const int b = idx / NV, v = idx - b*NV;
      pred[(size_t)b*NTT*NV + v] = 0.f; }
    if (idx < NB*NP){
      const int b = idx / NP, p = idx - b*NP;
      alph[(size_t)b*NTT*NP + p] = 0.f; }
    return;
  }
  lb -= 4000;
  if (lb < 9216){                       // ---- LayerNorm(features) -> bf16
    const float* x = feats + (size_t)lb * DE;
    float v[4]; float s = 0.f;
    #pragma unroll
    for (int i = 0; i < 4; ++i){
      const int idx = i*512 + tid;
      v[i] = (idx < DE) ? x[idx] : 0.f;
      s += v[i];
    }
    const float mean = block_sum512(s, sbuf8) * (1.f/DE);
    float q = 0.f;
    #pragma unroll
    for (int i = 0; i < 4; ++i){
      const int idx = i*512 + tid;
      if (idx < DE){ const float d = v[i] - mean; q += d*d; }
    }
    const float var = block_sum512(q, sbuf8) * (1.f/DE);
    const float rinv = rsqrtf(var + LN_EPS);
    #pragma unroll
    for (int i = 0; i < 4; ++i){
      const int idx = i*512 + tid;
      if (idx < DE)
        feats_bf[(size_t)lb*DE + idx] = f2bf((v[i]-mean)*rinv*ln_kv_g[idx] + ln_kv_b[idx]);
    }
    return;
  }
  lb -= 9216;
  if (lb < 224){                        // ---- mean over patches
    const int idx = lb*512 + tid;
    const int b = idx / DE, d = idx - b*DE;
    const float* p = feats + (size_t)b*NP*DE + d;
    float s = 0.f;
    for (int pp = 0; pp < NP; ++pp) s += p[(size_t)pp*DE];
    mean_a[idx] = s * (1.f/NP);
    return;
  }
  lb -= 224;
  if (lb < 4216){                       // ---- all weight transposes
    if (lb >= 4036){
      int l2 = lb - 4036;
      const int e0 = (l2 % 5)*64, k0 = (l2 / 5)*64;
      for (int i = tid; i < 4096; i += 512){
        const int k = i>>6, e2 = i&63;
        const int kg = k0 + k, e = e0 + e2;
        float v = 0.f;
        if (e < EM) v = (kg < DD) ? W_Lh[(size_t)kg*EM + e] : W_Lz[(size_t)(kg-DD)*EM + e];
        t[k][e2] = v;
      }
      __syncthreads();
      for (int i = tid; i < 4096; i += 512){
        const int e2 = i>>6, k = i&63;
        WLt[(size_t)(e0+e2)*KG1 + k0+k] = f2bf(t[k][e2]);
      }
      return;
    }
    const float* src; unsigned short* dst; int K, N, KPad, nx;
    if      (lb < 2500){             src=W_Lo; dst=wlo_t; K=EM; N=NV; KPad=KP; nx=500; }
    else if (lb < 2756){ lb -= 2500; src=Wh;   dst=whT;   K=DD; N=G4; KPad=DD; nx=32; }
    else if (lb < 2916){ lb -= 2756; src=Wu;   dst=wut;   K=EM; N=G4; KPad=KP; nx=32; }
    else if (lb < 3812){ lb -= 2916; src=Wa;   dst=wat;   K=DE; N=G4; KPad=DE; nx=32; }
    else               { lb -= 3812; src=Wk;   dst=WkT;   K=DE; N=DD; KPad=DE; nx=8;  }
    const int n0 = (lb % nx)*64, k0 = (lb / nx)*64;
    for (int i = tid; i < 4096; i += 512){
      const int k = i>>6, n = i&63;
      t[k][n] = (k0 + k < K) ? src[(size_t)(k0+k)*N + n0+n] : 0.f;
    }
    __syncthreads();
    for (int i = tid; i < 4096; i += 512){
      const int n = i>>6, k = i&63;
      dst[(size_t)(n0+n)*KPad + k0+k] = f2bf(t[k][n]);
    }
    return;
  }
  lb -= 4216;
  if (lb < 512){                        // ---- Wg = diag(g) * Wq
    const int idx = lb*512 + tid;
    const int k = idx >> 9;
    Wg[idx] = f2bf(g[k]*Wq[idx]);
    return;
  }
  // ---- prep: vq + u/voff/gw/cscal (1 block)
  {
    const int a = tid;
    {
      const float* row = Wq + (size_t)a*DA;
      float acc = 0.f;
      for (int j = 0; j < DA; ++j) acc = fmaf(row[j], bk[j], acc);
      vq[a] = acc;
    }
    float uu = 0.f, vv = 0.f;
    for (int k = 0; k < DD; ++k){
      const float wv = Wq[(size_t)k*DA + a];
      uu = fmaf(g[k],   wv, uu);
      vv = fmaf(bln[k], wv, vv);
    }
    const float vo = vv + bq[a];
    u_[a]   = uu;
    voff[a] = vo;
    gw[a]   = g[a]*Wbeta[a];
    const float c1 = block_sum512(g[a]*Wbeta[a], sbuf8);
    const float c2 = block_sum512(bln[a]*Wbeta[a], sbuf8);
    const float c3 = block_sum512(uu*bk[a], sbuf8);
    const float c4 = block_sum512(vo*bk[a], sbuf8);
    if (a == 0){ cscal[0]=c1; cscal[1]=c2+bbeta[0]; cscal[2]=c3; cscal[3]=c4; }
  }
}

// ======== PRE stage 2: KF | init_g | EU.  256 threads.
// blocks: KF[0,144) (keeps bid%8 XCD map), init[144,160), EU[160,1088).
__global__ __launch_bounds__(256) void k_pre2(
    const unsigned short* __restrict__ fb, const unsigned short* __restrict__ WkT,
    const float* __restrict__ mean_a,
    const float* __restrict__ W_ih, const float* __restrict__ b_ih,
    const float* __restrict__ W_ic, const float* __restrict__ b_ic,
    const float* __restrict__ emb_table, const int* __restrict__ captions,
    const unsigned short* __restrict__ wut,
    unsigned short* __restrict__ KF, float* __restrict__ hbuf,
    unsigned short* __restrict__ hstbf, float* __restrict__ cb0,
    float* __restrict__ eu){
  __shared__ alignas(16) char smem[49152];
  const int tid = threadIdx.x, w = tid>>6, lane = tid&63;
  int lb = blockIdx.x;
  if (lb < 144){                        // ---- KF big-tile
    char* Alds = smem; char* Blds = smem + 16384;
    const int wgid = (lb & 7)*18 + (lb >> 3);
    const int nt = wgid & 1, mt = wgid >> 1;
    f32x4 acc[8][4];
    #pragma unroll
    for (int i = 0; i < 8; ++i)
      #pragma unroll
      for (int j = 0; j < 4; ++j) acc[i][j] = (f32x4)(0.f);
    gemm_big<28>(fb, WkT, DE, DE, Alds, Blds, mt, nt, acc);
    const int ncol0 = nt*256 + w*64 + (lane&15);
    #pragma unroll
    for (int fm = 0; fm < 8; ++fm)
      #pragma unroll
      for (int r = 0; r < 4; ++r){
        const int row = mt*128 + fm*16 + (lane>>4)*4 + r;
        #pragma unroll
        for (int fn = 0; fn < 4; ++fn)
          KF[(size_t)row*DD + ncol0 + fn*16] = f2bf(acc[fm][fn][r]);
      }
    return;
  }
  lb -= 144;
  if (lb < 16){                         // ---- h0/c0 GEMM
    float* la = (float*)smem;                 // 64*68 floats
    float* lw = (float*)smem + 64*68;
    const int which = lb >> 3;
    const float* W    = which ? W_ic : W_ih;
    const float* bias = which ? b_ic : b_ih;
    float* out = which ? cb0 : hbuf;
    unsigned short* outbf = which ? nullptr : hstbf;
    const int j0 = (lb & 7)*64;
    const int tr = tid&15, tn = tid>>4;
    float acc[16] = {0.f};
    for (int a0 = 0; a0 < DE; a0 += 64){
      __syncthreads();
      for (int i = tid; i < 4096; i += 256){
        const int b = i>>6, k = i&63;
        la[k*68 + b] = mean_a[(size_t)b*DE + a0+k];
      }
      for (int i = tid; i < 4096; i += 256){
        const int k = i>>6, j = i&63;
        lw[k*68 + j] = W[(size_t)(a0+k)*DD + j0+j];
      }
      __syncthreads();
      for (int k = 0; k < 64; ++k){
        float av[4], bv[4];
        #pragma unroll
        for (int ii = 0; ii < 4; ++ii) av[ii] = la[k*68 + tr*4+ii];
        #pragma unroll
        for (int jj = 0; jj < 4; ++jj) bv[jj] = lw[k*68 + tn*4+jj];
        #pragma unroll
        for (int ii = 0; ii < 4; ++ii)
          #pragma unroll
          for (int jj = 0; jj < 4; ++jj)
            acc[ii*4+jj] = fmaf(av[ii], bv[jj], acc[ii*4+jj]);
      }
    }
    #pragma unroll
    for (int ii = 0; ii < 4; ++ii)
      #pragma unroll
      for (int jj = 0; jj < 4; ++jj){
        const size_t idx = (size_t)(tr*4+ii)*DD + j0 + tn*4+jj;
        const float val = acc[ii*4+jj] + bias[j0 + tn*4+jj];
        out[idx] = val;
        if (outbf) outbf[idx] = f2bf(val);
      }
    return;
  }
  lb -= 16;
  {                                     // ---- EU: emb(s)@Wu
    char* Alds = smem; char* Blds = smem + 8192;
    int* capL = (int*)(smem + 16384);
    const int jt = lb & 31, s = lb >> 5;
    if (tid < 64) capL[tid] = captions[tid*NTT + s];
    f32x4 acc[4];
    #pragma unroll
    for (int i = 0; i < 4; ++i) acc[i] = (f32x4)(0.f);
    for (int kt = 0; kt < 5; ++kt){
      __syncthreads();
      #pragma unroll
      for (int c = 0; c < 2; ++c){
        const int o = tid + c*256;
        const int m = o>>3, ks8 = o&7;
        const int e0 = kt*64 + ks8*8;
        const float* er = emb_table + (size_t)capL[m]*EM;
        ushort8v v;
        #pragma unroll
        for (int jj = 0; jj < 8; ++jj)
          v[jj] = (e0 + jj < EM) ? f2bf(er[e0 + jj]) : (unsigned short)0;
        *(ushort8v*)&Alds[m*128 + ((ks8 ^ (m&7))<<4)] = v;
      }
      stage_tile(wut + (size_t)jt*64*KP, KP, kt*64, Blds);
      __syncthreads();
      mma64(Alds, Blds, w, lane, acc);
    }
    const int j = jt*64 + w*16 + (lane&15);
    #pragma unroll
    for (int fm = 0; fm < 4; ++fm)
      #pragma unroll
      for (int r = 0; r < 4; ++r){
        const int b = fm*16 + (lane>>4)*4 + r;
        eu[((size_t)s*NB + b)*G4 + j] = acc[fm][r];
      }
  }
}

// ======== PRE stage 3: QG2 | sc12.  256 threads.
// blocks: QG2[0,144), sc12[144,2448) (4 rows/block, wave-level).
__global__ __launch_bounds__(256) void k_pre3(
    const unsigned short* __restrict__ KF, const unsigned short* __restrict__ Wg,
    const float* __restrict__ g_, const float* __restrict__ vq,
    const float* __restrict__ u_, const float* __restrict__ voff,
    const float* __restrict__ cscal,
    unsigned short* __restrict__ G2, float2* __restrict__ sc12){
  __shared__ alignas(16) char smem[49152];
  const int tid = threadIdx.x, w = tid>>6, lane = tid&63;
  int lb = blockIdx.x;
  if (lb < 144){                        // ---- G2 big-tile
    char* Alds = smem; char* Blds = smem + 16384;
    const int wgid = (lb & 7)*18 + (lb >> 3);
    const int nt = wgid & 1, mt = wgid >> 1;
    f32x4 acc[8][4];
    #pragma unroll
    for (int i = 0; i < 8; ++i)
      #pragma unroll
      for (int j = 0; j < 4; ++j) acc[i][j] = (f32x4)(0.f);
    gemm_big<8>(KF, Wg, DD, DD, Alds, Blds, mt, nt, acc);
    const int ncol0 = nt*256 + w*64 + (lane&15);
    float addv[4];
    #pragma unroll
    for (int fn = 0; fn < 4; ++fn){
      const int q = ncol0 + fn*16;
      addv[fn] = g_[q]*vq[q];
    }
    #pragma unroll
    for (int fm = 0; fm < 8; ++fm)
      #pragma unroll
      for (int r = 0; r < 4; ++r){
        const int row = mt*128 + fm*16 + (lane>>4)*4 + r;
        #pragma unroll
        for (int fn = 0; fn < 4; ++fn)
          G2[(size_t)row*DD + ncol0 + fn*16] = f2bf(acc[fm][fn][r] + addv[fn]);
      }
    return;
  }
  lb -= 144;
  {                                     // ---- sc12, 4 rows/block
    const int row = lb*4 + w;
    const unsigned short* kf = KF + (size_t)row*DD + lane*8;
    float s1 = 0.f, s2 = 0.f;
    #pragma unroll
    for (int j = 0; j < 8; ++j){
      const float kv = bf2f(kf[j]);
      s1 = fmaf(u_[lane*8 + j],   kv, s1);
      s2 = fmaf(voff[lane*8 + j], kv, s2);
    }
    s1 = wave_reduce_sum(s1);
    s2 = wave_reduce_sum(s2);
    if (lane == 0){
      float2 o; o.x = s1 + cscal[2]; o.y = s2 + cscal[3];
      sc12[row] = o;
    }
  }
}

// ======== per-step kernel A (r25: 4 slices/batch, 1 col/thread z)
__global__ __launch_bounds__(512) void k_A(
    const unsigned short* __restrict__ gp, const float* __restrict__ eu,
    const float* __restrict__ b_gates, const float* __restrict__ cin,
    float* __restrict__ cout, unsigned short* __restrict__ hst,
    const unsigned short* __restrict__ G2, const float2* __restrict__ sc12,
    const unsigned short* __restrict__ fb, const float* __restrict__ gw,
    const float* __restrict__ cscal, const int s, const int do_att,
    float* __restrict__ alph, unsigned short* __restrict__ zbf){
  __shared__ alignas(16) unsigned short hL[DD];
  __shared__ float sc[NP];
  __shared__ float al[NP];
  __shared__ float sredA[8*4];
  __shared__ float sbufM[8];
  __shared__ float sbufS[8];
  // XCD grouping: 4 sl-blocks of each b + 8 b's share an XCD (lin%8)
  int sl, b;
  if (gridDim.x == 1){ sl = 0; b = blockIdx.y; }
  else {
    const int lin = blockIdx.x + 4*blockIdx.y;
    const int xcd = lin & 7, i = lin >> 3;
    b = xcd*8 + (i & 7);
    sl = i >> 3;
  }
  const int tid = threadIdx.x;
  const int w = tid>>6, lane = tid&63;
  float hn;
  if (s == 0){
    const unsigned short hb = hst[(size_t)b*DD + tid];
    hn = bf2f(hb);
    hL[tid] = hb;
  } else {
    const int m = s - 1;
    unsigned short gv[4*KSPL];
    #pragma unroll
    for (int ks = 0; ks < KSPL; ++ks){
      const unsigned short* gr = gp + ((size_t)ks*NB + b)*G4 + tid;
      gv[ks*4+0] = gr[0];
      gv[ks*4+1] = gr[DD];
      gv[ks*4+2] = gr[2*DD];
      gv[ks*4+3] = gr[3*DD];
    }
    const float* eur = eu + ((size_t)m*NB + b)*G4 + tid;
    float gs0 = b_gates[tid]        + eur[0];
    float gs1 = b_gates[DD + tid]   + eur[DD];
    float gs2 = b_gates[2*DD + tid] + eur[2*DD];
    float gs3 = b_gates[3*DD + tid] + eur[3*DD];
    #pragma unroll
    for (int ks = 0; ks < KSPL; ++ks){
      gs0 += bf2f(gv[ks*4+0]); gs1 += bf2f(gv[ks*4+1]);
      gs2 += bf2f(gv[ks*4+2]); gs3 += bf2f(gv[ks*4+3]);
    }
    const size_t idx = (size_t)b*DD + tid;
    const float cn = sigm(gs1)*cin[idx] + sigm(gs0)*tanhf(gs3);
    hn = sigm(gs2)*tanhf(cn);
    cout[idx] = cn;
    const unsigned short hb = f2bf(hn);
    hst[(size_t)s*NB*DD + idx] = hb;
    hL[tid] = hb;
  }
  if (!do_att) return;
  float p1 = hn, p2 = hn*hn, p3 = hn*gw[tid];
  #pragma unroll
  for (int o = 32; o >= 1; o >>= 1){
    p1 += __shfl_xor(p1, o);
    p2 += __shfl_xor(p2, o);
    p3 += __shfl_xor(p3, o);
  }
  if (lane == 0){ sredA[w*4] = p1; sredA[w*4+1] = p2; sredA[w*4+2] = p3; }
  __syncthreads();
  float S1 = 0.f, S2 = 0.f, S3 = 0.f;
  #pragma unroll
  for (int i = 0; i < 8; ++i){
    S1 += sredA[i*4]; S2 += sredA[i*4+1]; S3 += sredA[i*4+2];
  }
  const float mean = S1*(1.f/512.f);
  const float var  = S2*(1.f/512.f) - mean*mean;
  const float rinv = rsqrtf(var + LN_EPS);
  const float beta = sigm(rinv*(S3 - mean*cscal[0]) + cscal[1]);
  const short8 hv = *(const short8*)&hL[lane*8];
  #pragma unroll 1
  for (int i0 = 0; i0 < 18; i0 += 9){
    short8 U[9];
    float2 SV[9];
    #pragma unroll
    for (int j = 0; j < 9; ++j){
      const int p = w + 8*(i0+j);
      U[j] = *(const short8*)&G2[(size_t)(b*NP + p)*DD + lane*8];
      if (lane == 0) SV[j] = sc12[b*NP + p];
    }
    #pragma unroll
    for (int j = 0; j < 9; ++j){
      float a2 = 0.f;
      #pragma unroll
      for (int q = 0; q < 8; ++q)
        a2 = fmaf(bf2f((unsigned short)U[j][q]), bf2f((unsigned short)hv[q]), a2);
      a2 = wave_reduce_sum(a2);
      if (lane == 0)
        sc[w + 8*(i0+j)] = RSCALE*(rinv*a2 - rinv*mean*SV[j].x + SV[j].y);
    }
  }
  __syncthreads();
  const float v = (tid < NP) ? sc[tid] : -1e30f;
  const float mv = wave_reduce_max(v);
  if (lane == 0) sbufM[w] = mv;
  __syncthreads();
  float mm = sbufM[0];
  #pragma unroll
  for (int i = 1; i < 8; ++i) mm = fmaxf(mm, sbufM[i]);
  const float e = (tid < NP) ? __expf(v - mm) : 0.f;
  const float sv = wave_reduce_sum(e);
  if (lane == 0) sbufS[w] = sv;
  __syncthreads();
  float ssum = 0.f;
  #pragma unroll
  for (int i = 0; i < 8; ++i) ssum += sbufS[i];
  if (tid < NP){
    const float a3 = e / ssum;
    al[tid] = a3;
    if (sl == 0) alph[((size_t)b*NTT + s + 1)*NP + tid] = a3;
  }
  __syncthreads();
  if (tid < 448){
    const int d = sl*448 + tid;        // 1 col/thread, 4 slices
    const unsigned short* fcol = fb + (size_t)b*NP*DE + d;
    float acc = 0.f;
    #pragma unroll 1
    for (int p0 = 0; p0 < NP; p0 += 36){
      unsigned short fv[36];
      #pragma unroll
      for (int j = 0; j < 36; ++j) fv[j] = fcol[(size_t)(p0+j)*DE];
      #pragma unroll
      for (int j = 0; j < 36; ++j)
        acc = fmaf(al[p0+j], bf2f(fv[j]), acc);
    }
    zbf[((size_t)s*NB + b)*DE + d] = f2bf(acc*beta);
  }
}

// ======== per-step kernel B (K-split 12, bf16 gp out).  grid (32, 12).
__global__ __launch_bounds__(256) void k_B(
    const unsigned short* __restrict__ hst, const unsigned short* __restrict__ zbf,
    const unsigned short* __restrict__ whT, const unsigned short* __restrict__ wat,
    const int s, unsigned short* __restrict__ gp){
  __shared__ char Alds[8192];
  __shared__ char Blds[8192];
  const int jt = blockIdx.x, ks = blockIdx.y;
  const int tid = threadIdx.x, w = tid>>6, lane = tid&63;
  const unsigned short* hrow = hst + (size_t)s*NB*DD;
  const unsigned short* zrow = zbf + (size_t)s*NB*DE;
  f32x4 acc[4];
  #pragma unroll
  for (int i = 0; i < 4; ++i) acc[i] = (f32x4)(0.f);
  for (int kt = 0; kt < 3; ++kt){
    const int k0 = ks*192 + kt*64;
    __syncthreads();
    if (k0 < DD) stage_tile(hrow, DD, k0, Alds);
    else         stage_tile(zrow, DE, k0 - DD, Alds);
    #pragma unroll
    for (int c2 = 0; c2 < 2; ++c2){
      const int o = tid + c2*256;
      const int m = o>>3, ks8 = o&7;
      const int col = (m>>4)*DD + jt*16 + (m&15);
      const unsigned short* src = (k0 < DD)
          ? whT + (size_t)col*DD + k0
          : wat + (size_t)col*DE + (k0 - DD);
      const ushort8v v = *(const ushort8v*)&src[ks8*8];
      *(ushort8v*)&Blds[m*128 + ((ks8 ^ (m&7))<<4)] = v;
    }
    __syncthreads();
    mma64(Alds, Blds, w, lane, acc);
  }
  const int jcol = jt*16 + (lane&15);
  unsigned short* gps = gp + (size_t)ks*NB*G4;
  #pragma unroll
  for (int fm = 0; fm < 4; ++fm)
    #pragma unroll
    for (int r = 0; r < 4; ++r){
      const int b = fm*16 + (lane>>4)*4 + r;
      gps[(size_t)b*G4 + w*DD + jcol] = f2bf(acc[fm][r]);
    }
}

// ---- post G1m: out_o partial, BIG-TILE.  grid (15 mt, 2 nt, 6 ksplit).
// M = NS*NB = 1856 (row guard), N = KP = 320 (col guard, B-row clamp).
__global__ __launch_bounds__(256) void k_G1m(const unsigned short* __restrict__ hstbf,
    const unsigned short* __restrict__ zbf, const unsigned short* __restrict__ WLt,
    float* __restrict__ g1p){
  __shared__ char Alds[128*128];
  __shared__ char Blds[256*128];
  const int mt = blockIdx.x, nt = blockIdx.y, ks6 = blockIdx.z;
  const int tid = threadIdx.x, w = tid>>6, lane = tid&63;
  f32x4 acc[8][4];
  #pragma unroll
  for (int i = 0; i < 8; ++i)
    #pragma unroll
    for (int j = 0; j < 4; ++j) acc[i][j] = (f32x4)(0.f);
  for (int kt = 0; kt < 6; ++kt){
    const int k0 = ks6*384 + kt*64;       // 64-aligned; never straddles DD
    __syncthreads();
    #pragma unroll
    for (int c2 = 0; c2 < 4; ++c2){
      const int o16 = tid + c2*256;
      const int m = o16>>3, ks8 = o16&7;
      const int r = mt*128 + m;
      ushort8v v;
      if (r < NS*NB){
        const int sS = r >> 6, bb = r & 63;
        const unsigned short* srcp = (k0 < DD)
            ? hstbf + ((size_t)(sS+1)*NB + bb)*DD + k0
            : zbf + ((size_t)sS*NB + bb)*DE + (k0 - DD);
        v = *(const ushort8v*)&srcp[ks8*8];
      } else {
        #pragma unroll
        for (int j = 0; j < 8; ++j) v[j] = 0;
      }
      *(ushort8v*)&Alds[m*128 + ((ks8 ^ (m&7))<<4)] = v;
    }
    #pragma unroll
    for (int c2 = 0; c2 < 8; ++c2){
      const int o16 = tid + c2*256;
      const int n = o16>>3, ks8 = o16&7;
      int nr = nt*256 + n;
      if (nr >= KP) nr = KP - 1;          // clamp (results discarded by guard)
      const ushort8v v = *(const ushort8v*)&WLt[(size_t)nr*KG1 + k0 + ks8*8];
      *(ushort8v*)&Blds[n*128 + ((ks8 ^ (n&7))<<4)] = v;
    }
    __syncthreads();
    #pragma unroll
    for (int ks = 0; ks < 2; ++ks){
      const int slot = ks*4 + (lane>>4);
      short8 af[8];
      #pragma unroll
      for (int fm = 0; fm < 8; ++fm){
        const int m = fm*16 + (lane&15);
        af[fm] = *(const short8*)&Alds[m*128 + ((slot ^ (m&7))<<4)];
      }
      #pragma unroll
      for (int fn = 0; fn < 4; ++fn){
        const int n = w*64 + fn*16 + (lane&15);
        const short8 bfv = *(const short8*)&Blds[n*128 + ((slot ^ (n&7))<<4)];
        #pragma unroll
        for (int fm = 0; fm < 8; ++fm)
          acc[fm][fn] = __builtin_amdgcn_mfma_f32_16x16x32_bf16(af[fm], bfv, acc[fm][fn], 0, 0, 0);
      }
    }
  }
  const int ncol0 = nt*256 + w*64 + (lane&15);
  float* dst = g1p + (size_t)ks6*NS*NB*KP;
  #pragma unroll
  for (int fm = 0; fm < 8; ++fm){
    #pragma unroll
    for (int r = 0; r < 4; ++r){
      const int row = mt*128 + fm*16 + (lane>>4)*4 + r;
      if (row < NS*NB){
        #pragma unroll
        for (int fn = 0; fn < 4; ++fn){
          const int e = ncol0 + fn*16;
          if (e < KP) dst[(size_t)row*KP + e] = acc[fm][fn][r];
        }
      }
    }
  }
}

// ---- post G1red: sum 6 partials + emb + biases -> outo bf16
__global__ __launch_bounds__(256) void k_G1red(const float* __restrict__ g1p,
    const float* __restrict__ b_Lh, const float* __restrict__ b_Lz,
    const float* __restrict__ emb_table, const int* __restrict__ captions,
    unsigned short* __restrict__ outo){
  const int idx = blockIdx.x*256 + threadIdx.x;
  const int row = idx / KP, e = idx - row*KP;
  const int s = row >> 6, b = row & 63;
  float v = 0.f;
  #pragma unroll
  for (int ks6 = 0; ks6 < 6; ++ks6) v += g1p[(size_t)ks6*NS*NB*KP + idx];
  if (e < EM){
    const int cap = captions[b*NTT + s];
    v += b_Lh[e] + b_Lz[e] + emb_table[(size_t)cap*EM + e];
  } else v = 0.f;
  outo[idx] = f2bf(v);
}

// ---- post G2: logits MFMA, M-tile 128.  1D grid 1875, bijective XCD
// swizzle (r18).  NONTEMPORAL stores.
__global__ __launch_bounds__(256) void k_G2(const unsigned short* __restrict__ Abf,
    const unsigned short* __restrict__ Bt, const float* __restrict__ b_Lo,
    float* __restrict__ pred){
  __shared__ char Alds[128*128];
  __shared__ char Blds[256*128];
  const int bid = blockIdx.x;
  const int xcd = bid & 7, idx8 = bid >> 3;
  const int wgid = (xcd < 3 ? xcd*235 : 705 + (xcd-3)*234) + idx8;
  const int nt = wgid / 15, mt = wgid - nt*15;
  const int tid = threadIdx.x, w = tid>>6, lane = tid&63;
  f32x4 acc[8][4];
  #pragma unroll
  for (int i = 0; i < 8; ++i)
    #pragma unroll
    for (int j = 0; j < 4; ++j)
      acc[i][j] = (f32x4)(0.f);
  gemm_big<5>(Abf, Bt, KP, KP, Alds, Blds, mt, nt, acc);
  const int ncol0 = nt*256 + w*64 + (lane&15);
  #pragma unroll
  for (int fm = 0; fm < 8; ++fm){
    #pragma unroll
    for (int r = 0; r < 4; ++r){
      const int row = mt*128 + fm*16 + (lane>>4)*4 + r;
      if (row < NS*NB){
        const int s = row >> 6, b = row & 63;
        float* prow = &pred[((size_t)b*NTT + s + 1)*NV + ncol0];
        #pragma unroll
        for (int fn = 0; fn < 4; ++fn)
          __builtin_nontemporal_store(acc[fm][fn][r] + b_Lo[ncol0 + fn*16],
                                      &prow[fn*16]);
      }
    }
  }
}

extern "C" void kernel_launch(void* const* d_in, const int* in_sizes, int n_in,
                              void* d_out, int out_size, void* d_ws, size_t ws_size,
                              hipStream_t stream){
  const float* features  = (const float*)d_in[0];
  const int*   captions  = (const int*)  d_in[1];
  const float* emb_table = (const float*)d_in[2];
  const float* ln_q_g = (const float*)d_in[3];
  const float* ln_q_b = (const float*)d_in[4];
  const float* ln_kv_g= (const float*)d_in[5];
  const float* ln_kv_b= (const float*)d_in[6];
  const float* Wq     = (const float*)d_in[7];
  const float* bq     = (const float*)d_in[8];
  const float* Wk     = (const float*)d_in[9];
  const float* bk     = (const float*)d_in[10];
  const float* Wbeta  = (const float*)d_in[11];
  const float* bbeta  = (const float*)d_in[12];
  const float* Wh     = (const float*)d_in[13];
  const float* Wu     = (const float*)d_in[14];
  const float* Wa     = (const float*)d_in[15];
  const float* b_gates= (const float*)d_in[16];
  const float* W_Lh   = (const float*)d_in[17];
  const float* b_Lh   = (const float*)d_in[18];
  const float* W_Lz   = (const float*)d_in[19];
  const float* b_Lz   = (const float*)d_in[20];
  const float* W_Lo   = (const float*)d_in[21];
  const float* b_Lo   = (const float*)d_in[22];
  const float* W_ih   = (const float*)d_in[23];
  const float* b_ih   = (const float*)d_in[24];
  const float* W_ic   = (const float*)d_in[25];
  const float* b_ic   = (const float*)d_in[26];

  float* pred = (float*)d_out;
  float* alph = pred + (size_t)NB * NTT * NV;

  char* w = (char*)d_ws;
  auto alloc = [&](size_t bytes) -> void* {
    void* p = (void*)w; w += (bytes + 255) & ~(size_t)255; return p;
  };
  unsigned short* feats_bf = (unsigned short*)alloc((size_t)NB*NP*DE * 2);
  unsigned short* wlo_t    = (unsigned short*)alloc((size_t)NV*KP * 2);
  unsigned short* whT      = (unsigned short*)alloc((size_t)G4*DD * 2);
  unsigned short* wut      = (unsigned short*)alloc((size_t)G4*KP * 2);
  unsigned short* wat      = (unsigned short*)alloc((size_t)G4*DE * 2);
  unsigned short* WkT      = (unsigned short*)alloc((size_t)DD*DE * 2);
  unsigned short* WLt      = (unsigned short*)alloc((size_t)KP*KG1 * 2);
  unsigned short* Wg       = (unsigned short*)alloc((size_t)DD*DD * 2);
  unsigned short* KFbf     = (unsigned short*)alloc((size_t)NB*NP*DD * 2);
  unsigned short* G2bf     = (unsigned short*)alloc((size_t)NB*NP*DD * 2);
  float2* sc12  = (float2*)alloc((size_t)NB*NP * 8);
  float* vq     = (float*)alloc((size_t)DD * 4);
  float* u_     = (float*)alloc((size_t)DD * 4);
  float* voff   = (float*)alloc((size_t)DD * 4);
  float* gw     = (float*)alloc((size_t)DD * 4);
  float* cscal  = (float*)alloc(16);
  float* mean_a = (float*)alloc((size_t)NB*DE * 4);
  float* hbuf   = (float*)alloc((size_t)NB*DD * 4);
  float* cb0    = (float*)alloc((size_t)NB*DD * 4);
  float* cb1    = (float*)alloc((size_t)NB*DD * 4);
  unsigned short* hstbf = (unsigned short*)alloc((size_t)(NS+1)*NB*DD * 2);
  unsigned short* zbf   = (unsigned short*)alloc((size_t)NS*NB*DE * 2);
  unsigned short* outo  = (unsigned short*)alloc((size_t)1920*KP * 2);
  unsigned short* gp    = (unsigned short*)alloc((size_t)KSPL*NB*G4 * 2);
  float* eu_all = (float*)alloc((size_t)NS*NB*G4 * 4);
  float* g1p    = (float*)alloc((size_t)6*NS*NB*KP * 4);
  float* cb[2] = { cb0, cb1 };

  // pre-pass: 3 dispatches
  k_pre1<<<dim3(18169), dim3(512), 0, stream>>>(features, ln_kv_g, ln_kv_b,
      W_Lo, Wh, Wu, Wa, Wk, W_Lh, W_Lz, Wq, bk, ln_q_g, ln_q_b, bq, Wbeta,
      bbeta, pred, alph, feats_bf, mean_a, wlo_t, whT, wut, wat, WkT, WLt,
      Wg, vq, u_, voff, gw, cscal);
  k_pre2<<<dim3(1088), dim3(256), 0, stream>>>(feats_bf, WkT, mean_a,
      W_ih, b_ih, W_ic, b_ic, emb_table, captions, wut,
      KFbf, hbuf, hstbf, cb0, eu_all);
  k_pre3<<<dim3(2448), dim3(256), 0, stream>>>(KFbf, Wg, ln_q_g, vq,
      u_, voff, cscal, G2bf, sc12);

  for (int s = 0; s < NS; ++s){
    k_A<<<dim3(4, NB), dim3(512), 0, stream>>>(gp, eu_all, b_gates,
        cb[(s & 1) ^ 1], cb[s & 1], hstbf, G2bf, sc12, feats_bf,
        gw, cscal, s, 1, alph, zbf);
    k_B<<<dim3(32, KSPL), dim3(256), 0, stream>>>(hstbf, zbf, whT, wat, s, gp);
  }
  // final LSTM -> h_29
  k_A<<<dim3(1, NB), dim3(512), 0, stream>>>(gp, eu_all, b_gates,
      cb[(NS & 1) ^ 1], cb[NS & 1], hstbf, G2bf, sc12, feats_bf,
      gw, cscal, NS, 0, alph, zbf);

  // post-pass: 3 dispatches (r22-proven split)
  k_G1m<<<dim3(15, 2, 6), dim3(256), 0, stream>>>(hstbf, zbf, WLt, g1p);
  k_G1red<<<dim3((NS*NB*KP)/256), dim3(256), 0, stream>>>(g1p, b_Lh, b_Lz,
      emb_table, captions, outo);
  k_G2<<<dim3(1875), dim3(256), 0, stream>>>(outo, wlo_t, b_Lo, pred);
}